// Round 4
// baseline (549.607 us; speedup 1.0000x reference)
//
#include <hip/hip_runtime.h>
#include <cmath>

#define H 8
#define SEQ 2048
#define EDIM 512
#define HD 64
#define ROWS 8
#define EPSF 1e-15f

// workspace layout (floats)
#define FLAG_OFF  0
#define WF_OFF    16
#define ZN_OFF    (WF_OFF + 3 * EDIM * EDIM)
#define QKV_OFF   (ZN_OFF + 3 * EDIM)
#define STATS_OFF (QKV_OFF + 3 * SEQ * EDIM)

__device__ __forceinline__ float bf2f(unsigned short u){
  union { unsigned int i; float f; } v; v.i = ((unsigned int)u) << 16; return v.f;
}

// P0: dtype probe. bf16-interpret first 256 u16 of query; fp32 data decodes to
// huge magnitudes (uniform exponent byte) w.p. ~1, real bf16 stays ~0.1.
__global__ void probe_kernel(const unsigned short* __restrict__ q, int* __restrict__ flag){
  const int t = threadIdx.x;  // 64
  float mx = 0.f;
  #pragma unroll
  for (int j = 0; j < 4; ++j) mx = fmaxf(mx, fabsf(bf2f(q[t * 4 + j])));
  #pragma unroll
  for (int m = 32; m >= 1; m >>= 1) mx = fmaxf(mx, __shfl_xor(mx, m, 64));
  if (t == 0) *flag = (mx > 1000.f) ? 1 : 0;
}

// P1: normalize the three weight matrices to fp32 in workspace.
__global__ __launch_bounds__(256) void wcvt_kernel(
    const void* __restrict__ Wq, const void* __restrict__ Wk, const void* __restrict__ Wv,
    const int* __restrict__ flag, float* __restrict__ Wf)
{
  const int p = blockIdx.y;
  const void* W = (p == 0) ? Wq : ((p == 1) ? Wk : Wv);
  const int base = (blockIdx.x * 256 + threadIdx.x) * 4;
  float* dst = Wf + (size_t)p * EDIM * EDIM + base;
  if (*flag){
    float4 v = *(const float4*)((const float*)W + base);
    *(float4*)dst = v;
  } else {
    ushort4 w = *(const ushort4*)((const unsigned short*)W + base);
    dst[0] = bf2f(w.x); dst[1] = bf2f(w.y); dst[2] = bf2f(w.z); dst[3] = bf2f(w.w);
  }
}

// K0: column norms zn[p][o] = max(||W[:,o]||, eps), from fp32 Wf
__global__ void zn_kernel(const float* __restrict__ Wf, float* __restrict__ zn){
  const int p = blockIdx.x;
  const int o = threadIdx.x;
  const float* W = Wf + (size_t)p * EDIM * EDIM;
  float acc = 0.f;
  for (int i = 0; i < EDIM; ++i){ float w = W[i * EDIM + o]; acc += w * w; }
  zn[p * EDIM + o] = fmaxf(sqrtf(acc), EPSF);
}

// K1: HNN++ Poincare linear layer for q/k/v. 8 rows per block, 2 outputs per thread.
// Writes fp32 qkv in [p][h][s][d] layout + per-head squared norms stats[p][h][s].
__global__ __launch_bounds__(256) void hlinear_kernel(
    const void* __restrict__ Xq, const void* __restrict__ Xk, const void* __restrict__ Xv,
    const float* __restrict__ Wf,
    const void* __restrict__ Bq, const void* __restrict__ Bk, const void* __restrict__ Bv,
    const float* __restrict__ zn_all, const int* __restrict__ flag,
    float* __restrict__ qkv, float* __restrict__ stats)
{
  const int p = blockIdx.y;
  const void* X  = (p == 0) ? Xq : ((p == 1) ? Xk : Xv);
  const void* Bb = (p == 0) ? Bq : ((p == 1) ? Bk : Bv);
  const float* W = Wf + (size_t)p * EDIM * EDIM;
  const float* zn = zn_all + p * EDIM;
  const int r0 = blockIdx.x * ROWS;
  const int t  = threadIdx.x;
  const int isf32 = *flag;

  __shared__ float smem[ROWS * EDIM];   // first: x transposed [i][row]; later: w values [row][o]
  __shared__ float x2p[4][ROWS];
  __shared__ float x2s[ROWS];
  __shared__ float sw2[ROWS];

  // stage x (transposed, [i][rr]) + per-row |x|^2 partials
  float part[ROWS];
  #pragma unroll
  for (int rr = 0; rr < ROWS; ++rr) part[rr] = 0.f;
  if (isf32){
    const float* Xf = (const float*)X;
    for (int i = t; i < EDIM; i += 256){
      #pragma unroll
      for (int rr = 0; rr < ROWS; ++rr){
        float xv = Xf[(size_t)(r0 + rr) * EDIM + i];
        smem[i * ROWS + rr] = xv;
        part[rr] += xv * xv;
      }
    }
  } else {
    const unsigned short* Xb = (const unsigned short*)X;
    for (int i = t; i < EDIM; i += 256){
      #pragma unroll
      for (int rr = 0; rr < ROWS; ++rr){
        float xv = bf2f(Xb[(size_t)(r0 + rr) * EDIM + i]);
        smem[i * ROWS + rr] = xv;
        part[rr] += xv * xv;
      }
    }
  }
  #pragma unroll
  for (int rr = 0; rr < ROWS; ++rr){
    float v = part[rr];
    #pragma unroll
    for (int m = 32; m >= 1; m >>= 1) v += __shfl_xor(v, m, 64);
    if ((t & 63) == 0) x2p[t >> 6][rr] = v;
  }
  __syncthreads();
  if (t < ROWS) x2s[t] = x2p[0][t] + x2p[1][t] + x2p[2][t] + x2p[3][t];
  __syncthreads();

  // GEMM: outputs o0, o0+1 for 8 rows
  const int o0 = 2 * t;
  float acc[ROWS][2];
  #pragma unroll
  for (int rr = 0; rr < ROWS; ++rr){ acc[rr][0] = 0.f; acc[rr][1] = 0.f; }

  #pragma unroll 4
  for (int i = 0; i < EDIM; ++i){
    float2 z = *(const float2*)&W[i * EDIM + o0];
    float4 xa = *(const float4*)&smem[i * ROWS];
    float4 xb = *(const float4*)&smem[i * ROWS + 4];
    float xr[8] = {xa.x, xa.y, xa.z, xa.w, xb.x, xb.y, xb.z, xb.w};
    #pragma unroll
    for (int rr = 0; rr < ROWS; ++rr){
      acc[rr][0] += xr[rr] * z.x;
      acc[rr][1] += xr[rr] * z.y;
    }
  }
  __syncthreads();   // done reading xT; smem reused for w values

  // elementwise h_linear transform (c = 1, sqrt(c) = 1)
  {
    float rb0, rb1;
    if (isf32){ rb0 = ((const float*)Bb)[o0]; rb1 = ((const float*)Bb)[o0 + 1]; }
    else      { rb0 = bf2f(((const unsigned short*)Bb)[o0]);
                rb1 = bf2f(((const unsigned short*)Bb)[o0 + 1]); }
    float znv = zn[o0], znv1 = zn[o0 + 1];
    float ch0 = coshf(2.f * rb0), sh0 = sinhf(2.f * rb0);
    float ch1 = coshf(2.f * rb1), sh1 = sinhf(2.f * rb1);
    #pragma unroll
    for (int rr = 0; rr < ROWS; ++rr){
      float lam = 2.f / (1.f - x2s[rr]);
      float a0 = (acc[rr][0] * lam / znv)  * ch0 - (lam - 1.f) * sh0;
      float a1 = (acc[rr][1] * lam / znv1) * ch1 - (lam - 1.f) * sh1;
      smem[rr * EDIM + o0]     = sinhf(2.f * znv  * asinhf(a0));
      smem[rr * EDIM + o0 + 1] = sinhf(2.f * znv1 * asinhf(a1));
    }
  }
  __syncthreads();

  // per-row sum of w^2 (32 threads per row)
  {
    int row = t >> 5, l = t & 31;
    float s = 0.f;
    for (int o = l; o < EDIM; o += 32){ float wv = smem[row * EDIM + o]; s += wv * wv; }
    #pragma unroll
    for (int m = 16; m >= 1; m >>= 1) s += __shfl_xor(s, m, 64);
    if (l == 0) sw2[row] = s;
  }
  __syncthreads();

  // normalize, write qkv (fp32) + per-head squared norms
  const int h0 = t >> 5;   // = o0 >> 6
  const int d0 = o0 & 63;
  #pragma unroll
  for (int rr = 0; rr < ROWS; ++rr){
    float inv = 1.f / (1.f + sqrtf(1.f + sw2[rr]));
    float v0 = smem[rr * EDIM + o0] * inv;
    float v1 = smem[rr * EDIM + o0 + 1] * inv;
    int s = r0 + rr;
    float* dst = qkv + (((size_t)p * H + h0) * SEQ + s) * HD + d0;
    dst[0] = v0; dst[1] = v1;
    float ss = v0 * v0 + v1 * v1;
    #pragma unroll
    for (int m = 16; m >= 1; m >>= 1) ss += __shfl_xor(ss, m, 64);
    if ((t & 31) == 0) stats[((size_t)p * H + h0) * SEQ + s] = ss;
  }
}

// K3: fused causal hyperbolic attention + gyromidpoint.
// Block = 256 threads = 4 waves = 4 consecutive q-rows of one head; shared K/V LDS tiles.
__global__ __launch_bounds__(256) void attn_kernel(
    const float* __restrict__ qkv, const float* __restrict__ stats,
    const void* __restrict__ tau, const void* __restrict__ gam,
    const int* __restrict__ flag,
    float* __restrict__ out, float beta_scale)
{
  const int h = blockIdx.y;
  const int t = threadIdx.x;
  const int w = t >> 6, lane = t & 63;
  const int qrow = blockIdx.x * 4 + w;

  const float* qp  = qkv + ((size_t)(0 * H + h) * SEQ) * HD;
  const float* kp  = qkv + ((size_t)(1 * H + h) * SEQ) * HD;
  const float* vp  = qkv + ((size_t)(2 * H + h) * SEQ) * HD;
  const float* q2s = stats + (size_t)(0 * H + h) * SEQ;
  const float* k2s = stats + (size_t)(1 * H + h) * SEQ;
  const float* v2s = stats + (size_t)(2 * H + h) * SEQ;

  __shared__ float KR[64][68];   // stride 68: 16B-aligned rows, uniform bank spread
  __shared__ float VR[64][68];
  __shared__ float k2t[64], v2t[64];
  __shared__ float wls[4][64];
  __shared__ float qsh[256];

  // stage the block's 4 q-rows, then pull own row into registers
  qsh[t] = qp[((size_t)blockIdx.x * 4 + (t >> 6)) * HD + (t & 63)];
  __syncthreads();
  float qreg[64];
  #pragma unroll
  for (int d4 = 0; d4 < 16; ++d4){
    float4 qv = *(const float4*)&qsh[w * 64 + 4 * d4];
    qreg[4*d4+0] = qv.x; qreg[4*d4+1] = qv.y; qreg[4*d4+2] = qv.z; qreg[4*d4+3] = qv.w;
  }
  const float q2 = q2s[qrow];
  float tauv, gamv;
  if (*flag){ tauv = ((const float*)tau)[0]; gamv = ((const float*)gam)[0]; }
  else      { tauv = bf2f(((const unsigned short*)tau)[0]);
              gamv = bf2f(((const unsigned short*)gam)[0]); }
  const float e_tau = expf(tauv);

  float num = 0.f, den = 0.f;
  const int maxq = blockIdx.x * 4 + 3;
  const int ntiles = (maxq + 64) >> 6;

  for (int kt = 0; kt < ntiles; ++kt){
    const int k0 = kt << 6;
    __syncthreads();   // previous phase B done with VR
    #pragma unroll 4
    for (int m = 0; m < 16; ++m){
      int jj = (t >> 6) + 4 * m;
      int kk = k0 + jj; if (kk > SEQ - 1) kk = SEQ - 1;
      KR[jj][lane] = kp[(size_t)kk * HD + lane];
      VR[jj][lane] = vp[(size_t)kk * HD + lane];
    }
    if (t < 64){
      int kk = k0 + t; if (kk > SEQ - 1) kk = SEQ - 1;
      k2t[t] = k2s[kk];
      v2t[t] = v2s[kk];
    }
    __syncthreads();

    // phase A: this lane owns k = k0+lane
    {
      float s = 0.f;
      #pragma unroll
      for (int d4 = 0; d4 < 16; ++d4){
        float4 kv = *(const float4*)&KR[lane][4 * d4];
        s += qreg[4*d4+0]*kv.x + qreg[4*d4+1]*kv.y + qreg[4*d4+2]*kv.z + qreg[4*d4+3]*kv.w;
      }
      const int k = k0 + lane;
      const bool valid = (k <= qrow);
      float k2 = k2t[lane];
      float diff2 = fmaxf(q2 + k2 - 2.f * s, 0.f);
      float denr = (1.f - q2) * (1.f - k2);
      float arg = 1.f + 2.f * diff2 / denr;
      arg = fmaxf(arg, 1.f + 1e-7f);
      float dist = acoshf(arg);
      float wv = valid ? expf(-dist * e_tau - gamv) : 0.f;
      float lamk = 2.f / (1.f - v2t[lane]);
      den += wv * (lamk - 1.f);
      wls[w][lane] = wv * lamk;
    }
    __syncthreads();

    // phase B: this lane owns dim d = lane
    #pragma unroll
    for (int j4 = 0; j4 < 16; ++j4){
      float4 wv4 = *(const float4*)&wls[w][4 * j4];
      num += wv4.x * VR[4*j4+0][lane];
      num += wv4.y * VR[4*j4+1][lane];
      num += wv4.z * VR[4*j4+2][lane];
      num += wv4.w * VR[4*j4+3][lane];
    }
  }

  // gyromidpoint epilogue
  #pragma unroll
  for (int m = 32; m >= 1; m >>= 1) den += __shfl_xor(den, m, 64);
  den = fmaxf(den, EPSF);
  float g = num / den;
  float gsq = g * g;
  #pragma unroll
  for (int m = 32; m >= 1; m >>= 1) gsq += __shfl_xor(gsq, m, 64);
  float gn = fmaxf(sqrtf(gsq), EPSF);
  float x = fminf(gn, 1.f - 1e-7f);
  float tt = x / (1.f + sqrtf(1.f - x * x));   // tanh(0.5*atanh(x)) closed form
  float res = (tt * g / gn) * beta_scale;
  out[(size_t)qrow * EDIM + h * HD + lane] = res;   // fp32 output (reference dtype)
}

extern "C" void kernel_launch(void* const* d_in, const int* in_sizes, int n_in,
                              void* d_out, int out_size, void* d_ws, size_t ws_size,
                              hipStream_t stream){
  const void* Xq  = d_in[0];
  const void* Xk  = d_in[1];
  const void* Xv  = d_in[2];
  const void* Wq  = d_in[3];
  const void* Wk  = d_in[4];
  const void* Wv  = d_in[5];
  const void* Bq  = d_in[6];
  const void* Bk  = d_in[7];
  const void* Bv  = d_in[8];
  const void* tau = d_in[9];
  const void* gam = d_in[10];

  float* wsf   = (float*)d_ws;
  int*   flag  = (int*)(wsf + FLAG_OFF);
  float* Wf    = wsf + WF_OFF;
  float* zn    = wsf + ZN_OFF;
  float* qkv   = wsf + QKV_OFF;
  float* stats = wsf + STATS_OFF;

  // beta-concatenation scale: B(E/2,1/2)/B(hd/2,1/2)
  double lb1 = lgamma(EDIM / 2.0) + lgamma(0.5) - lgamma(EDIM / 2.0 + 0.5);
  double lb2 = lgamma(HD / 2.0)   + lgamma(0.5) - lgamma(HD / 2.0 + 0.5);
  float beta_scale = (float)exp(lb1 - lb2);

  probe_kernel<<<dim3(1), dim3(64), 0, stream>>>((const unsigned short*)Xq, flag);
  wcvt_kernel<<<dim3(256, 3), dim3(256), 0, stream>>>(Wq, Wk, Wv, flag, Wf);
  zn_kernel<<<dim3(3), dim3(EDIM), 0, stream>>>(Wf, zn);
  hlinear_kernel<<<dim3(SEQ / ROWS, 3), dim3(256), 0, stream>>>(
      Xq, Xk, Xv, Wf, Bq, Bk, Bv, zn, flag, qkv, stats);
  attn_kernel<<<dim3(SEQ / 4, H), dim3(256), 0, stream>>>(
      qkv, stats, tau, gam, flag, (float*)d_out, beta_scale);
}

// Round 5
// 480.439 us; speedup vs baseline: 1.1440x; 1.1440x over previous
//
#include <hip/hip_runtime.h>
#include <cmath>

#define H 8
#define SEQ 2048
#define EDIM 512
#define HD 64
#define ROWS 8
#define EPSF 1e-15f

typedef short bf16x8 __attribute__((ext_vector_type(8)));
typedef float f32x4 __attribute__((ext_vector_type(4)));

// workspace layout (float offsets; all 16B-aligned)
#define FLAG_OFF  0
#define WF_OFF    16
#define ZN_OFF    (WF_OFF + 3 * EDIM * EDIM)
#define STATS_OFF (ZN_OFF + 3 * EDIM)
#define QKVB_OFF  (STATS_OFF + 3 * H * SEQ)            // u16 region: 3*H*SEQ*HD u16
#define VT_OFF    (QKVB_OFF + (3 * H * SEQ * HD) / 2)  // u16 region: H*80*SEQ u16

__device__ __forceinline__ float bf2f(unsigned short u){
  union { unsigned int i; float f; } v; v.i = ((unsigned int)u) << 16; return v.f;
}
__device__ __forceinline__ unsigned short f2bf(float f){
  union { float f; unsigned int i; } v; v.f = f;
  unsigned int x = v.i;
  unsigned int r = (x + 0x7fffu + ((x >> 16) & 1u)) >> 16;
  return (unsigned short)r;
}

// P0: dtype probe (fp32 data bf16-decodes to huge magnitudes w.p. ~1)
__global__ void probe_kernel(const unsigned short* __restrict__ q, int* __restrict__ flag){
  const int t = threadIdx.x;  // 64
  float mx = 0.f;
  #pragma unroll
  for (int j = 0; j < 4; ++j) mx = fmaxf(mx, fabsf(bf2f(q[t * 4 + j])));
  #pragma unroll
  for (int m = 32; m >= 1; m >>= 1) mx = fmaxf(mx, __shfl_xor(mx, m, 64));
  if (t == 0) *flag = (mx > 1000.f) ? 1 : 0;
}

// P1: normalize weights to fp32 in workspace.
__global__ __launch_bounds__(256) void wcvt_kernel(
    const void* __restrict__ Wq, const void* __restrict__ Wk, const void* __restrict__ Wv,
    const int* __restrict__ flag, float* __restrict__ Wf)
{
  const int p = blockIdx.y;
  const void* W = (p == 0) ? Wq : ((p == 1) ? Wk : Wv);
  const int base = (blockIdx.x * 256 + threadIdx.x) * 4;
  float* dst = Wf + (size_t)p * EDIM * EDIM + base;
  if (*flag){
    float4 v = *(const float4*)((const float*)W + base);
    *(float4*)dst = v;
  } else {
    ushort4 w = *(const ushort4*)((const unsigned short*)W + base);
    dst[0] = bf2f(w.x); dst[1] = bf2f(w.y); dst[2] = bf2f(w.z); dst[3] = bf2f(w.w);
  }
}

// K0: column norms zn[p][o]
__global__ void zn_kernel(const float* __restrict__ Wf, float* __restrict__ zn){
  const int p = blockIdx.x;
  const int o = threadIdx.x;
  const float* W = Wf + (size_t)p * EDIM * EDIM;
  float acc = 0.f;
  for (int i = 0; i < EDIM; ++i){ float w = W[i * EDIM + o]; acc += w * w; }
  zn[p * EDIM + o] = fmaxf(sqrtf(acc), EPSF);
}

// K1: hyperbolic linear. Writes bf16 q/k/v [p][h][s][d] + per-head squared norms of the
// ROUNDED values (keeps MFMA-computed diagonal distances consistent -> ~0).
__global__ __launch_bounds__(256) void hlinear_kernel(
    const void* __restrict__ Xq, const void* __restrict__ Xk, const void* __restrict__ Xv,
    const float* __restrict__ Wf,
    const void* __restrict__ Bq, const void* __restrict__ Bk, const void* __restrict__ Bv,
    const float* __restrict__ zn_all, const int* __restrict__ flag,
    unsigned short* __restrict__ qkvb, float* __restrict__ stats)
{
  const int p = blockIdx.y;
  const void* X  = (p == 0) ? Xq : ((p == 1) ? Xk : Xv);
  const void* Bb = (p == 0) ? Bq : ((p == 1) ? Bk : Bv);
  const float* W = Wf + (size_t)p * EDIM * EDIM;
  const float* zn = zn_all + p * EDIM;
  const int r0 = blockIdx.x * ROWS;
  const int t  = threadIdx.x;
  const int isf32 = *flag;

  __shared__ float smem[ROWS * EDIM];
  __shared__ float x2p[4][ROWS];
  __shared__ float x2s[ROWS];
  __shared__ float sw2[ROWS];

  float part[ROWS];
  #pragma unroll
  for (int rr = 0; rr < ROWS; ++rr) part[rr] = 0.f;
  if (isf32){
    const float* Xf = (const float*)X;
    for (int i = t; i < EDIM; i += 256){
      #pragma unroll
      for (int rr = 0; rr < ROWS; ++rr){
        float xv = Xf[(size_t)(r0 + rr) * EDIM + i];
        smem[i * ROWS + rr] = xv;
        part[rr] += xv * xv;
      }
    }
  } else {
    const unsigned short* Xb = (const unsigned short*)X;
    for (int i = t; i < EDIM; i += 256){
      #pragma unroll
      for (int rr = 0; rr < ROWS; ++rr){
        float xv = bf2f(Xb[(size_t)(r0 + rr) * EDIM + i]);
        smem[i * ROWS + rr] = xv;
        part[rr] += xv * xv;
      }
    }
  }
  #pragma unroll
  for (int rr = 0; rr < ROWS; ++rr){
    float v = part[rr];
    #pragma unroll
    for (int m = 32; m >= 1; m >>= 1) v += __shfl_xor(v, m, 64);
    if ((t & 63) == 0) x2p[t >> 6][rr] = v;
  }
  __syncthreads();
  if (t < ROWS) x2s[t] = x2p[0][t] + x2p[1][t] + x2p[2][t] + x2p[3][t];
  __syncthreads();

  const int o0 = 2 * t;
  float acc[ROWS][2];
  #pragma unroll
  for (int rr = 0; rr < ROWS; ++rr){ acc[rr][0] = 0.f; acc[rr][1] = 0.f; }

  #pragma unroll 4
  for (int i = 0; i < EDIM; ++i){
    float2 z = *(const float2*)&W[i * EDIM + o0];
    float4 xa = *(const float4*)&smem[i * ROWS];
    float4 xb = *(const float4*)&smem[i * ROWS + 4];
    float xr[8] = {xa.x, xa.y, xa.z, xa.w, xb.x, xb.y, xb.z, xb.w};
    #pragma unroll
    for (int rr = 0; rr < ROWS; ++rr){
      acc[rr][0] += xr[rr] * z.x;
      acc[rr][1] += xr[rr] * z.y;
    }
  }
  __syncthreads();

  {
    float rb0, rb1;
    if (isf32){ rb0 = ((const float*)Bb)[o0]; rb1 = ((const float*)Bb)[o0 + 1]; }
    else      { rb0 = bf2f(((const unsigned short*)Bb)[o0]);
                rb1 = bf2f(((const unsigned short*)Bb)[o0 + 1]); }
    float znv = zn[o0], znv1 = zn[o0 + 1];
    float ch0 = coshf(2.f * rb0), sh0 = sinhf(2.f * rb0);
    float ch1 = coshf(2.f * rb1), sh1 = sinhf(2.f * rb1);
    #pragma unroll
    for (int rr = 0; rr < ROWS; ++rr){
      float lam = 2.f / (1.f - x2s[rr]);
      float a0 = (acc[rr][0] * lam / znv)  * ch0 - (lam - 1.f) * sh0;
      float a1 = (acc[rr][1] * lam / znv1) * ch1 - (lam - 1.f) * sh1;
      smem[rr * EDIM + o0]     = sinhf(2.f * znv  * asinhf(a0));
      smem[rr * EDIM + o0 + 1] = sinhf(2.f * znv1 * asinhf(a1));
    }
  }
  __syncthreads();

  {
    int row = t >> 5, l = t & 31;
    float s = 0.f;
    for (int o = l; o < EDIM; o += 32){ float wv = smem[row * EDIM + o]; s += wv * wv; }
    #pragma unroll
    for (int m = 16; m >= 1; m >>= 1) s += __shfl_xor(s, m, 64);
    if (l == 0) sw2[row] = s;
  }
  __syncthreads();

  const int h0 = t >> 5;
  const int d0 = o0 & 63;
  #pragma unroll
  for (int rr = 0; rr < ROWS; ++rr){
    float inv = 1.f / (1.f + sqrtf(1.f + sw2[rr]));
    unsigned short b0 = f2bf(smem[rr * EDIM + o0] * inv);
    unsigned short b1 = f2bf(smem[rr * EDIM + o0 + 1] * inv);
    float r0v = bf2f(b0), r1v = bf2f(b1);   // rounded values for stats
    int s = r0 + rr;
    unsigned int* dst = (unsigned int*)&qkvb[(((size_t)p * H + h0) * SEQ + s) * HD + d0];
    *dst = (unsigned int)b0 | ((unsigned int)b1 << 16);
    float ss = r0v * r0v + r1v * r1v;
    #pragma unroll
    for (int m = 16; m >= 1; m >>= 1) ss += __shfl_xor(ss, m, 64);
    if ((t & 31) == 0) stats[((size_t)p * H + h0) * SEQ + s] = ss;
  }
}

// K2: build VT' = [lambda_k * v | lambda_k - 1 | zero-pad] bf16, layout [h][80][SEQ]
// (B-fragment friendly: 8 consecutive k per lane) from Vb [h][s][64].
__global__ __launch_bounds__(256) void vt_kernel(
    const unsigned short* __restrict__ Vb, const float* __restrict__ v2s,
    unsigned short* __restrict__ VT)
{
  const int h = blockIdx.y;
  const int k0 = blockIdx.x * 64;
  const int t = threadIdx.x;
  __shared__ float tld[64][65];
  __shared__ float lam[64];
  if (t < 64){ float v2 = v2s[(size_t)h * SEQ + k0 + t]; lam[t] = 2.f / (1.f - v2); }
  #pragma unroll
  for (int i = 0; i < 16; ++i){
    int idx = t * 16 + i;
    int kk = idx >> 6, d = idx & 63;
    tld[kk][d] = bf2f(Vb[((size_t)h * SEQ + k0 + kk) * HD + d]);
  }
  __syncthreads();
  const int d = t >> 2;
  const int kb = (t & 3) * 16;
  #pragma unroll
  for (int i = 0; i < 16; ++i){
    int k = kb + i;
    float val = tld[k][d] * lam[k];
    VT[((size_t)h * 80 + d) * SEQ + k0 + k] = f2bf(val);
  }
  if (t < 64) VT[((size_t)h * 80 + 64) * SEQ + k0 + t] = f2bf(lam[t] - 1.f);
  #pragma unroll
  for (int i = 0; i < 4; ++i){
    int e = t + 256 * i;
    if (e < 960){
      int row = 65 + (e >> 6), kk = e & 63;
      VT[((size_t)h * 80 + row) * SEQ + k0 + kk] = 0;
    }
  }
}

// K3: MFMA flash-style causal hyperbolic attention + gyromidpoint.
// Block = 4 waves, each wave owns a 16-row q-tile of a 64-row block; no K/V LDS
// staging (B-frags straight from L2); P goes C-layout -> A-layout via per-wave LDS.
__global__ __launch_bounds__(256) void attn_mfma_kernel(
    const unsigned short* __restrict__ Qb, const unsigned short* __restrict__ Kb,
    const unsigned short* __restrict__ VT,
    const float* __restrict__ q2s_all, const float* __restrict__ k2s_all,
    const void* __restrict__ tau, const void* __restrict__ gam,
    const int* __restrict__ flag,
    float* __restrict__ out, float beta_scale)
{
  const int h  = blockIdx.y;
  const int qt = blockIdx.x;            // 64-row q block
  const int t = threadIdx.x;
  const int w = t >> 6, lane = t & 63;
  const int col = lane & 15, quad = lane >> 4;
  const int q0 = qt * 64 + w * 16;      // this wave's 16-row q tile

  const unsigned short* Qh  = Qb + (size_t)h * SEQ * HD;
  const unsigned short* Kh  = Kb + (size_t)h * SEQ * HD;
  const unsigned short* VTh = VT + (size_t)h * 80 * SEQ;
  const float* q2s = q2s_all + (size_t)h * SEQ;
  const float* k2s = k2s_all + (size_t)h * SEQ;

  __shared__ unsigned short P_lds[4][64][16];   // per-wave [k][q] bf16

  // Q A-frags (fixed across k loop): A[m=col][kdim=quad*8+j (+32*half)]
  bf16x8 qf0 = *(const bf16x8*)&Qh[(size_t)(q0 + col) * HD + quad * 8];
  bf16x8 qf1 = *(const bf16x8*)&Qh[(size_t)(q0 + col) * HD + 32 + quad * 8];

  // per-lane q2 for the C/D rows it owns (row = quad*4 + r)
  float q2r[4], omq2[4];
  #pragma unroll
  for (int r = 0; r < 4; ++r){
    q2r[r] = q2s[q0 + quad * 4 + r];
    omq2[r] = 1.f - q2r[r];
  }

  float tauv, gamv;
  if (*flag){ tauv = ((const float*)tau)[0]; gamv = ((const float*)gam)[0]; }
  else      { tauv = bf2f(((const unsigned short*)tau)[0]);
              gamv = bf2f(((const unsigned short*)gam)[0]); }
  const float e_tau = expf(tauv);

  f32x4 pv[5];
  #pragma unroll
  for (int nt = 0; nt < 5; ++nt) pv[nt] = (f32x4){0.f, 0.f, 0.f, 0.f};

  const int ntk = qt + 1;   // uniform across the block's 4 waves

  for (int kt = 0; kt < ntk; ++kt){
    const int k0 = kt * 64;

    // ---- QK^T (4 n-tiles of 16 k) + dist/exp -> P (bf16) ----
    unsigned short pvals[16];
    #pragma unroll
    for (int nt = 0; nt < 4; ++nt){
      const int kbase = k0 + 16 * nt + col;
      f32x4 sacc = (f32x4){0.f, 0.f, 0.f, 0.f};
      bf16x8 kf0 = *(const bf16x8*)&Kh[(size_t)kbase * HD + quad * 8];
      bf16x8 kf1 = *(const bf16x8*)&Kh[(size_t)kbase * HD + 32 + quad * 8];
      sacc = __builtin_amdgcn_mfma_f32_16x16x32_bf16(qf0, kf0, sacc, 0, 0, 0);
      sacc = __builtin_amdgcn_mfma_f32_16x16x32_bf16(qf1, kf1, sacc, 0, 0, 0);
      const float k2v = k2s[kbase];
      const float omk2 = 1.f - k2v;
      #pragma unroll
      for (int r = 0; r < 4; ++r){
        const int qi = q0 + quad * 4 + r;
        float diff2 = fmaxf(q2r[r] + k2v - 2.f * sacc[r], 0.f);
        float arg = 1.f + 2.f * diff2 / (omq2[r] * omk2);
        arg = fmaxf(arg, 1.f + 1e-7f);
        float dist = acoshf(arg);
        float wv = (kbase <= qi) ? expf(-dist * e_tau - gamv) : 0.f;
        pvals[nt * 4 + r] = f2bf(wv);
      }
    }
    // write P to per-wave LDS in [k][q] layout (b64 per n-tile)
    #pragma unroll
    for (int nt = 0; nt < 4; ++nt){
      uint2 pk;
      pk.x = (unsigned int)pvals[nt * 4 + 0] | ((unsigned int)pvals[nt * 4 + 1] << 16);
      pk.y = (unsigned int)pvals[nt * 4 + 2] | ((unsigned int)pvals[nt * 4 + 3] << 16);
      *(uint2*)&P_lds[w][16 * nt + col][quad * 4] = pk;
    }
    __syncthreads();   // uniform (ntk same for all waves); orders P write -> read

    // ---- P (A-layout) x VT' -> num(64 dims) + den(col 64) ----
    #pragma unroll
    for (int half = 0; half < 2; ++half){
      bf16x8 pf;
      #pragma unroll
      for (int j = 0; j < 8; ++j)
        pf[j] = (short)P_lds[w][32 * half + quad * 8 + j][col];
      #pragma unroll
      for (int nt = 0; nt < 5; ++nt){
        bf16x8 vf = *(const bf16x8*)&VTh[(size_t)(16 * nt + col) * SEQ + k0 + 32 * half + quad * 8];
        pv[nt] = __builtin_amdgcn_mfma_f32_16x16x32_bf16(pf, vf, pv[nt], 0, 0, 0);
      }
    }
  }

  // ---- gyromidpoint epilogue ----
  // den lives in pv[4] at col==0 lanes; broadcast within each quad group
  #pragma unroll
  for (int r = 0; r < 4; ++r){
    float den = __shfl(pv[4][r], lane & 48, 64);
    den = fmaxf(den, EPSF);
    float inv_den = 1.f / den;
    float g[4];
    float gsq = 0.f;
    #pragma unroll
    for (int nt = 0; nt < 4; ++nt){ g[nt] = pv[nt][r] * inv_den; gsq += g[nt] * g[nt]; }
    #pragma unroll
    for (int m = 8; m >= 1; m >>= 1) gsq += __shfl_xor(gsq, m, 64);
    float gn = fmaxf(sqrtf(gsq), EPSF);
    float x = fminf(gn, 1.f - 1e-7f);
    float tt = x / (1.f + sqrtf(1.f - x * x));   // tanh(0.5*atanh(x))
    float scl = (tt / gn) * beta_scale;
    const int q = q0 + quad * 4 + r;
    #pragma unroll
    for (int nt = 0; nt < 4; ++nt)
      out[(size_t)q * EDIM + h * HD + 16 * nt + col] = g[nt] * scl;
  }
}

extern "C" void kernel_launch(void* const* d_in, const int* in_sizes, int n_in,
                              void* d_out, int out_size, void* d_ws, size_t ws_size,
                              hipStream_t stream){
  const void* Xq  = d_in[0];
  const void* Xk  = d_in[1];
  const void* Xv  = d_in[2];
  const void* Wq  = d_in[3];
  const void* Wk  = d_in[4];
  const void* Wv  = d_in[5];
  const void* Bq  = d_in[6];
  const void* Bk  = d_in[7];
  const void* Bv  = d_in[8];
  const void* tau = d_in[9];
  const void* gam = d_in[10];

  float* wsf   = (float*)d_ws;
  int*   flag  = (int*)(wsf + FLAG_OFF);
  float* Wf    = wsf + WF_OFF;
  float* zn    = wsf + ZN_OFF;
  float* stats = wsf + STATS_OFF;
  unsigned short* qkvb = (unsigned short*)(wsf + QKVB_OFF);
  unsigned short* VT   = (unsigned short*)(wsf + VT_OFF);

  unsigned short* Qb = qkvb;
  unsigned short* Kb = qkvb + (size_t)H * SEQ * HD;
  unsigned short* Vb = qkvb + (size_t)2 * H * SEQ * HD;
  float* q2s = stats;
  float* k2s = stats + (size_t)H * SEQ;
  float* v2s = stats + (size_t)2 * H * SEQ;

  double lb1 = lgamma(EDIM / 2.0) + lgamma(0.5) - lgamma(EDIM / 2.0 + 0.5);
  double lb2 = lgamma(HD / 2.0)   + lgamma(0.5) - lgamma(HD / 2.0 + 0.5);
  float beta_scale = (float)exp(lb1 - lb2);

  probe_kernel<<<dim3(1), dim3(64), 0, stream>>>((const unsigned short*)Xq, flag);
  wcvt_kernel<<<dim3(256, 3), dim3(256), 0, stream>>>(Wq, Wk, Wv, flag, Wf);
  zn_kernel<<<dim3(3), dim3(EDIM), 0, stream>>>(Wf, zn);
  hlinear_kernel<<<dim3(SEQ / ROWS, 3), dim3(256), 0, stream>>>(
      Xq, Xk, Xv, Wf, Bq, Bk, Bv, zn, flag, qkvb, stats);
  vt_kernel<<<dim3(SEQ / 64, H), dim3(256), 0, stream>>>(Vb, v2s, VT);
  attn_mfma_kernel<<<dim3(SEQ / 64, H), dim3(256), 0, stream>>>(
      Qb, Kb, VT, q2s, k2s, tau, gam, flag, (float*)d_out, beta_scale);
}

// Round 7
// 372.871 us; speedup vs baseline: 1.4740x; 1.2885x over previous
//
#include <hip/hip_runtime.h>
#include <cmath>

#define H 8
#define SEQ 2048
#define EDIM 512
#define HD 64
#define ROWS 8
#define EPSF 1e-15f

typedef short bf16x8 __attribute__((ext_vector_type(8)));
typedef float f32x4 __attribute__((ext_vector_type(4)));

// workspace layout (float offsets; all 16B-aligned)
#define FLAG_OFF  0
#define WF_OFF    16
#define ZN_OFF    (WF_OFF + 3 * EDIM * EDIM)
#define STATS_OFF (ZN_OFF + 3 * EDIM)
#define QKVB_OFF  (STATS_OFF + 3 * H * SEQ)            // u16 region: 3*H*SEQ*HD u16
#define VT_OFF    (QKVB_OFF + (3 * H * SEQ * HD) / 2)  // u16 region: H*80*SEQ u16

__device__ __forceinline__ float bf2f(unsigned short u){
  union { unsigned int i; float f; } v; v.i = ((unsigned int)u) << 16; return v.f;
}
__device__ __forceinline__ unsigned short f2bf(float f){
  union { float f; unsigned int i; } v; v.f = f;
  unsigned int x = v.i;
  unsigned int r = (x + 0x7fffu + ((x >> 16) & 1u)) >> 16;
  return (unsigned short)r;
}

// P0: dtype probe (fp32 data bf16-decodes to huge magnitudes w.p. ~1)
__global__ void probe_kernel(const unsigned short* __restrict__ q, int* __restrict__ flag){
  const int t = threadIdx.x;  // 64
  float mx = 0.f;
  #pragma unroll
  for (int j = 0; j < 4; ++j) mx = fmaxf(mx, fabsf(bf2f(q[t * 4 + j])));
  #pragma unroll
  for (int m = 32; m >= 1; m >>= 1) mx = fmaxf(mx, __shfl_xor(mx, m, 64));
  if (t == 0) *flag = (mx > 1000.f) ? 1 : 0;
}

// P1: normalize weights to fp32 in workspace.
__global__ __launch_bounds__(256) void wcvt_kernel(
    const void* __restrict__ Wq, const void* __restrict__ Wk, const void* __restrict__ Wv,
    const int* __restrict__ flag, float* __restrict__ Wf)
{
  const int p = blockIdx.y;
  const void* W = (p == 0) ? Wq : ((p == 1) ? Wk : Wv);
  const int base = (blockIdx.x * 256 + threadIdx.x) * 4;
  float* dst = Wf + (size_t)p * EDIM * EDIM + base;
  if (*flag){
    float4 v = *(const float4*)((const float*)W + base);
    *(float4*)dst = v;
  } else {
    ushort4 w = *(const ushort4*)((const unsigned short*)W + base);
    dst[0] = bf2f(w.x); dst[1] = bf2f(w.y); dst[2] = bf2f(w.z); dst[3] = bf2f(w.w);
  }
}

// K0: column norms zn[p][o]
__global__ void zn_kernel(const float* __restrict__ Wf, float* __restrict__ zn){
  const int p = blockIdx.x;
  const int o = threadIdx.x;
  const float* W = Wf + (size_t)p * EDIM * EDIM;
  float acc = 0.f;
  for (int i = 0; i < EDIM; ++i){ float w = W[i * EDIM + o]; acc += w * w; }
  zn[p * EDIM + o] = fmaxf(sqrtf(acc), EPSF);
}

// K1: hyperbolic linear. Writes bf16 q/k/v [p][h][s][d] + per-head squared norms of the
// ROUNDED values (keeps MFMA-computed diagonal distances consistent -> ~0).
__global__ __launch_bounds__(256) void hlinear_kernel(
    const void* __restrict__ Xq, const void* __restrict__ Xk, const void* __restrict__ Xv,
    const float* __restrict__ Wf,
    const void* __restrict__ Bq, const void* __restrict__ Bk, const void* __restrict__ Bv,
    const float* __restrict__ zn_all, const int* __restrict__ flag,
    unsigned short* __restrict__ qkvb, float* __restrict__ stats)
{
  const int p = blockIdx.y;
  const void* X  = (p == 0) ? Xq : ((p == 1) ? Xk : Xv);
  const void* Bb = (p == 0) ? Bq : ((p == 1) ? Bk : Bv);
  const float* W = Wf + (size_t)p * EDIM * EDIM;
  const float* zn = zn_all + p * EDIM;
  const int r0 = blockIdx.x * ROWS;
  const int t  = threadIdx.x;
  const int isf32 = *flag;

  __shared__ float smem[ROWS * EDIM];
  __shared__ float x2p[4][ROWS];
  __shared__ float x2s[ROWS];
  __shared__ float sw2[ROWS];

  float part[ROWS];
  #pragma unroll
  for (int rr = 0; rr < ROWS; ++rr) part[rr] = 0.f;
  if (isf32){
    const float* Xf = (const float*)X;
    for (int i = t; i < EDIM; i += 256){
      #pragma unroll
      for (int rr = 0; rr < ROWS; ++rr){
        float xv = Xf[(size_t)(r0 + rr) * EDIM + i];
        smem[i * ROWS + rr] = xv;
        part[rr] += xv * xv;
      }
    }
  } else {
    const unsigned short* Xb = (const unsigned short*)X;
    for (int i = t; i < EDIM; i += 256){
      #pragma unroll
      for (int rr = 0; rr < ROWS; ++rr){
        float xv = bf2f(Xb[(size_t)(r0 + rr) * EDIM + i]);
        smem[i * ROWS + rr] = xv;
        part[rr] += xv * xv;
      }
    }
  }
  #pragma unroll
  for (int rr = 0; rr < ROWS; ++rr){
    float v = part[rr];
    #pragma unroll
    for (int m = 32; m >= 1; m >>= 1) v += __shfl_xor(v, m, 64);
    if ((t & 63) == 0) x2p[t >> 6][rr] = v;
  }
  __syncthreads();
  if (t < ROWS) x2s[t] = x2p[0][t] + x2p[1][t] + x2p[2][t] + x2p[3][t];
  __syncthreads();

  const int o0 = 2 * t;
  float acc[ROWS][2];
  #pragma unroll
  for (int rr = 0; rr < ROWS; ++rr){ acc[rr][0] = 0.f; acc[rr][1] = 0.f; }

  #pragma unroll 4
  for (int i = 0; i < EDIM; ++i){
    float2 z = *(const float2*)&W[i * EDIM + o0];
    float4 xa = *(const float4*)&smem[i * ROWS];
    float4 xb = *(const float4*)&smem[i * ROWS + 4];
    float xr[8] = {xa.x, xa.y, xa.z, xa.w, xb.x, xb.y, xb.z, xb.w};
    #pragma unroll
    for (int rr = 0; rr < ROWS; ++rr){
      acc[rr][0] += xr[rr] * z.x;
      acc[rr][1] += xr[rr] * z.y;
    }
  }
  __syncthreads();

  {
    float rb0, rb1;
    if (isf32){ rb0 = ((const float*)Bb)[o0]; rb1 = ((const float*)Bb)[o0 + 1]; }
    else      { rb0 = bf2f(((const unsigned short*)Bb)[o0]);
                rb1 = bf2f(((const unsigned short*)Bb)[o0 + 1]); }
    float znv = zn[o0], znv1 = zn[o0 + 1];
    float ch0 = coshf(2.f * rb0), sh0 = sinhf(2.f * rb0);
    float ch1 = coshf(2.f * rb1), sh1 = sinhf(2.f * rb1);
    #pragma unroll
    for (int rr = 0; rr < ROWS; ++rr){
      float lam = 2.f / (1.f - x2s[rr]);
      float a0 = (acc[rr][0] * lam / znv)  * ch0 - (lam - 1.f) * sh0;
      float a1 = (acc[rr][1] * lam / znv1) * ch1 - (lam - 1.f) * sh1;
      smem[rr * EDIM + o0]     = sinhf(2.f * znv  * asinhf(a0));
      smem[rr * EDIM + o0 + 1] = sinhf(2.f * znv1 * asinhf(a1));
    }
  }
  __syncthreads();

  {
    int row = t >> 5, l = t & 31;
    float s = 0.f;
    for (int o = l; o < EDIM; o += 32){ float wv = smem[row * EDIM + o]; s += wv * wv; }
    #pragma unroll
    for (int m = 16; m >= 1; m >>= 1) s += __shfl_xor(s, m, 64);
    if (l == 0) sw2[row] = s;
  }
  __syncthreads();

  const int h0 = t >> 5;
  const int d0 = o0 & 63;
  #pragma unroll
  for (int rr = 0; rr < ROWS; ++rr){
    float inv = 1.f / (1.f + sqrtf(1.f + sw2[rr]));
    unsigned short b0 = f2bf(smem[rr * EDIM + o0] * inv);
    unsigned short b1 = f2bf(smem[rr * EDIM + o0 + 1] * inv);
    float r0v = bf2f(b0), r1v = bf2f(b1);   // rounded values for stats
    int s = r0 + rr;
    unsigned int* dst = (unsigned int*)&qkvb[(((size_t)p * H + h0) * SEQ + s) * HD + d0];
    *dst = (unsigned int)b0 | ((unsigned int)b1 << 16);
    float ss = r0v * r0v + r1v * r1v;
    #pragma unroll
    for (int m = 16; m >= 1; m >>= 1) ss += __shfl_xor(ss, m, 64);
    if ((t & 31) == 0) stats[((size_t)p * H + h0) * SEQ + s] = ss;
  }
}

// K2: build VT' = [lambda_k * v | lambda_k - 1 | zero-pad] bf16, layout [h][80][SEQ]
__global__ __launch_bounds__(256) void vt_kernel(
    const unsigned short* __restrict__ Vb, const float* __restrict__ v2s,
    unsigned short* __restrict__ VT)
{
  const int h = blockIdx.y;
  const int k0 = blockIdx.x * 64;
  const int t = threadIdx.x;
  __shared__ float tld[64][65];
  __shared__ float lam[64];
  if (t < 64){ float v2 = v2s[(size_t)h * SEQ + k0 + t]; lam[t] = 2.f / (1.f - v2); }
  #pragma unroll
  for (int i = 0; i < 16; ++i){
    int idx = t * 16 + i;
    int kk = idx >> 6, d = idx & 63;
    tld[kk][d] = bf2f(Vb[((size_t)h * SEQ + k0 + kk) * HD + d]);
  }
  __syncthreads();
  const int d = t >> 2;
  const int kb = (t & 3) * 16;
  #pragma unroll
  for (int i = 0; i < 16; ++i){
    int k = kb + i;
    float val = tld[k][d] * lam[k];
    VT[((size_t)h * 80 + d) * SEQ + k0 + k] = f2bf(val);
  }
  if (t < 64) VT[((size_t)h * 80 + 64) * SEQ + k0 + t] = f2bf(lam[t] - 1.f);
  #pragma unroll
  for (int i = 0; i < 4; ++i){
    int e = t + 256 * i;
    if (e < 960){
      int row = 65 + (e >> 6), kk = e & 63;
      VT[((size_t)h * 80 + row) * SEQ + k0 + kk] = 0;
    }
  }
}

// K3: MFMA causal hyperbolic attention, S^T orientation, shuffle-based P transpose,
// no LDS / no barriers. One wave per block; wave bx handles q-tiles {bx, 127-bx}
// (129 k-16-tiles each -> perfectly balanced). Fast __logf/__expf for dist/exp.
__global__ __launch_bounds__(64) void attn_mfma_kernel(
    const unsigned short* __restrict__ Qb, const unsigned short* __restrict__ Kb,
    const unsigned short* __restrict__ VT,
    const float* __restrict__ q2s_all, const float* __restrict__ k2s_all,
    const void* __restrict__ tau, const void* __restrict__ gam,
    const int* __restrict__ flag,
    float* __restrict__ out, float beta_scale)
{
  const int h  = blockIdx.y;
  const int bx = blockIdx.x;             // 0..63
  const int lane = threadIdx.x;
  const int col = lane & 15, quad = lane >> 4;

  const unsigned short* Qh  = Qb + (size_t)h * SEQ * HD;
  const unsigned short* Kh  = Kb + (size_t)h * SEQ * HD;
  const unsigned short* VTh = VT + (size_t)h * 80 * SEQ;
  const float* q2s = q2s_all + (size_t)h * SEQ;
  const float* k2s = k2s_all + (size_t)h * SEQ;

  float tauv, gamv;
  if (*flag){ tauv = ((const float*)tau)[0]; gamv = ((const float*)gam)[0]; }
  else      { tauv = bf2f(((const unsigned short*)tau)[0]);
              gamv = bf2f(((const unsigned short*)gam)[0]); }
  const float e_tau = expf(tauv);

  // shuffle sources for C-layout -> A-layout transpose (uniform per lane)
  const int srcA = ((quad & 1) * 2) * 16 + col;
  const int srcB = srcA + 16;
  const int tsel = quad >> 1;

  #pragma unroll
  for (int ti = 0; ti < 2; ++ti){
    const int tile = ti ? (127 - bx) : bx;
    const int q0 = tile * 16;

    // Q as B-frag: B[kdim=quad*8+j][n=col] -> row (q0+col), dims quad*8.. (+32)
    bf16x8 qf0 = *(const bf16x8*)&Qh[(size_t)(q0 + col) * HD + quad * 8];
    bf16x8 qf1 = *(const bf16x8*)&Qh[(size_t)(q0 + col) * HD + 32 + quad * 8];
    const float q2 = q2s[q0 + col];
    const float omq2 = 1.f - q2;
    const int qmax = q0 + col;

    f32x4 pv[5];
    #pragma unroll
    for (int nt = 0; nt < 5; ++nt) pv[nt] = (f32x4){0.f, 0.f, 0.f, 0.f};

    const int nch = (tile + 4) >> 2;   // ceil((16*tile+16)/64)
    for (int kc = 0; kc < nch; ++kc){
      #pragma unroll
      for (int half = 0; half < 2; ++half){
        const int kb32 = kc * 64 + half * 32;
        unsigned int tlo[2], thi[2];
        #pragma unroll
        for (int tt = 0; tt < 2; ++tt){
          const int kbase = kb32 + 16 * tt;
          // K as A-frag: A[m=col -> key kbase+col][kdim=quad*8+j]
          bf16x8 kf0 = *(const bf16x8*)&Kh[(size_t)(kbase + col) * HD + quad * 8];
          bf16x8 kf1 = *(const bf16x8*)&Kh[(size_t)(kbase + col) * HD + 32 + quad * 8];
          f32x4 s = (f32x4){0.f, 0.f, 0.f, 0.f};
          s = __builtin_amdgcn_mfma_f32_16x16x32_bf16(kf0, qf0, s, 0, 0, 0);
          s = __builtin_amdgcn_mfma_f32_16x16x32_bf16(kf1, qf1, s, 0, 0, 0);
          // S^T: lane holds [key=kbase+quad*4+r][q=q0+col]
          float4 k2q = *(const float4*)&k2s[kbase + quad * 4];
          unsigned short pb[4];
          #pragma unroll
          for (int r = 0; r < 4; ++r){
            float k2 = (r == 0) ? k2q.x : (r == 1) ? k2q.y : (r == 2) ? k2q.z : k2q.w;
            float diff2 = fmaxf(q2 + k2 - 2.f * s[r], 0.f);
            float u = 2.f * diff2 / (omq2 * (1.f - k2));
            u = fmaxf(u, 1e-7f);                           // ref's arg>=1+1e-7 clamp
            float z = 1.f + u + sqrtf(u * (u + 2.f));      // arg + sqrt(arg^2-1), stable
            float dist = __logf(z);                        // acosh via stable log form
            float wv = __expf(-e_tau * dist - gamv);       // exp attention weight
            int key = kbase + quad * 4 + r;
            if (key > qmax) wv = 0.f;
            pb[r] = f2bf(wv);
          }
          tlo[tt] = (unsigned int)pb[0] | ((unsigned int)pb[1] << 16);
          thi[tt] = (unsigned int)pb[2] | ((unsigned int)pb[3] << 16);
        }
        // cross-lane transpose: pf[j] = P[q=col][key=kb32+quad*8+j]
        unsigned int a0 = (unsigned int)__shfl((int)tlo[0], srcA, 64);
        unsigned int a1 = (unsigned int)__shfl((int)tlo[1], srcA, 64);
        unsigned int b0 = (unsigned int)__shfl((int)thi[0], srcA, 64);
        unsigned int b1 = (unsigned int)__shfl((int)thi[1], srcA, 64);
        unsigned int c0 = (unsigned int)__shfl((int)tlo[0], srcB, 64);
        unsigned int c1 = (unsigned int)__shfl((int)tlo[1], srcB, 64);
        unsigned int d0 = (unsigned int)__shfl((int)thi[0], srcB, 64);
        unsigned int d1 = (unsigned int)__shfl((int)thi[1], srcB, 64);
        union { uint4 u; bf16x8 v; } pw;
        pw.u.x = tsel ? a1 : a0;
        pw.u.y = tsel ? b1 : b0;
        pw.u.z = tsel ? c1 : c0;
        pw.u.w = tsel ? d1 : d0;
        // P x VT' (K=32): B[kdim=quad*8+j][n=col] = VT[odim=16nt+col][key]
        #pragma unroll
        for (int nt = 0; nt < 5; ++nt){
          bf16x8 vf = *(const bf16x8*)&VTh[(size_t)(16 * nt + col) * SEQ + kb32 + quad * 8];
          pv[nt] = __builtin_amdgcn_mfma_f32_16x16x32_bf16(pw.v, vf, pv[nt], 0, 0, 0);
        }
      }
    }

    // gyromidpoint epilogue: lane holds O[q=q0+quad*4+r][odim=16nt+col]
    #pragma unroll
    for (int r = 0; r < 4; ++r){
      float den = __shfl(pv[4][r], quad * 16, 64);   // col 64 lives at col==0 lanes
      den = fmaxf(den, EPSF);
      float inv_den = 1.f / den;
      float g[4];
      float gsq = 0.f;
      #pragma unroll
      for (int nt = 0; nt < 4; ++nt){ g[nt] = pv[nt][r] * inv_den; gsq += g[nt] * g[nt]; }
      #pragma unroll
      for (int m = 8; m >= 1; m >>= 1) gsq += __shfl_xor(gsq, m, 64);
      float gn = fmaxf(sqrtf(gsq), EPSF);
      float x = fminf(gn, 1.f - 1e-7f);
      float tt = x / (1.f + sqrtf(1.f - x * x));   // tanh(0.5*atanh(x))
      float scl = (tt / gn) * beta_scale;
      const int q = q0 + quad * 4 + r;
      #pragma unroll
      for (int nt = 0; nt < 4; ++nt)
        out[(size_t)q * EDIM + h * HD + 16 * nt + col] = g[nt] * scl;
    }
  }
}

extern "C" void kernel_launch(void* const* d_in, const int* in_sizes, int n_in,
                              void* d_out, int out_size, void* d_ws, size_t ws_size,
                              hipStream_t stream){
  const void* Xq  = d_in[0];
  const void* Xk  = d_in[1];
  const void* Xv  = d_in[2];
  const void* Wq  = d_in[3];
  const void* Wk  = d_in[4];
  const void* Wv  = d_in[5];
  const void* Bq  = d_in[6];
  const void* Bk  = d_in[7];
  const void* Bv  = d_in[8];
  const void* tau = d_in[9];
  const void* gam = d_in[10];

  float* wsf   = (float*)d_ws;
  int*   flag  = (int*)(wsf + FLAG_OFF);
  float* Wf    = wsf + WF_OFF;
  float* zn    = wsf + ZN_OFF;
  float* stats = wsf + STATS_OFF;
  unsigned short* qkvb = (unsigned short*)(wsf + QKVB_OFF);
  unsigned short* VT   = (unsigned short*)(wsf + VT_OFF);

  unsigned short* Qb = qkvb;
  unsigned short* Kb = qkvb + (size_t)H * SEQ * HD;
  unsigned short* Vb = qkvb + (size_t)2 * H * SEQ * HD;
  float* q2s = stats;
  float* k2s = stats + (size_t)H * SEQ;
  float* v2s = stats + (size_t)2 * H * SEQ;

  double lb1 = lgamma(EDIM / 2.0) + lgamma(0.5) - lgamma(EDIM / 2.0 + 0.5);
  double lb2 = lgamma(HD / 2.0)   + lgamma(0.5) - lgamma(HD / 2.0 + 0.5);
  float beta_scale = (float)exp(lb1 - lb2);

  probe_kernel<<<dim3(1), dim3(64), 0, stream>>>((const unsigned short*)Xq, flag);
  wcvt_kernel<<<dim3(256, 3), dim3(256), 0, stream>>>(Wq, Wk, Wv, flag, Wf);
  zn_kernel<<<dim3(3), dim3(EDIM), 0, stream>>>(Wf, zn);
  hlinear_kernel<<<dim3(SEQ / ROWS, 3), dim3(256), 0, stream>>>(
      Xq, Xk, Xv, Wf, Bq, Bk, Bv, zn, flag, qkvb, stats);
  vt_kernel<<<dim3(SEQ / 64, H), dim3(256), 0, stream>>>(Vb, v2s, VT);
  attn_mfma_kernel<<<dim3(64, H), dim3(64), 0, stream>>>(
      Qb, Kb, VT, q2s, k2s, tau, gam, flag, (float*)d_out, beta_scale);
}

// Round 8
// 239.450 us; speedup vs baseline: 2.2953x; 1.5572x over previous
//
#include <hip/hip_runtime.h>
#include <cmath>

#define H 8
#define SEQ 2048
#define EDIM 512
#define HD 64
#define ROWS 16
#define XSTR 20
#define EPSF 1e-15f

typedef short bf16x8 __attribute__((ext_vector_type(8)));
typedef float f32x4 __attribute__((ext_vector_type(4)));

// workspace layout (float offsets; all 16B-aligned)
#define FLAG_OFF  0
#define WF_OFF    16
#define ZN_OFF    (WF_OFF + 3 * EDIM * EDIM)
#define STATS_OFF (ZN_OFF + 3 * EDIM)
#define QKVB_OFF  (STATS_OFF + 3 * H * SEQ)            // u16 region: 3*H*SEQ*HD u16
#define VT_OFF    (QKVB_OFF + (3 * H * SEQ * HD) / 2)  // u16 region: H*80*SEQ u16

__device__ __forceinline__ float bf2f(unsigned short u){
  union { unsigned int i; float f; } v; v.i = ((unsigned int)u) << 16; return v.f;
}
__device__ __forceinline__ unsigned short f2bf(float f){
  union { float f; unsigned int i; } v; v.f = f;
  unsigned int x = v.i;
  unsigned int r = (x + 0x7fffu + ((x >> 16) & 1u)) >> 16;
  return (unsigned short)r;
}

// P0: dtype probe (fp32 data bf16-decodes to huge magnitudes w.p. ~1)
__global__ void probe_kernel(const unsigned short* __restrict__ q, int* __restrict__ flag){
  const int t = threadIdx.x;  // 64
  float mx = 0.f;
  #pragma unroll
  for (int j = 0; j < 4; ++j) mx = fmaxf(mx, fabsf(bf2f(q[t * 4 + j])));
  #pragma unroll
  for (int m = 32; m >= 1; m >>= 1) mx = fmaxf(mx, __shfl_xor(mx, m, 64));
  if (t == 0) *flag = (mx > 1000.f) ? 1 : 0;
}

// P1: normalize weights to fp32 in workspace.
__global__ __launch_bounds__(256) void wcvt_kernel(
    const void* __restrict__ Wq, const void* __restrict__ Wk, const void* __restrict__ Wv,
    const int* __restrict__ flag, float* __restrict__ Wf)
{
  const int p = blockIdx.y;
  const void* W = (p == 0) ? Wq : ((p == 1) ? Wk : Wv);
  const int base = (blockIdx.x * 256 + threadIdx.x) * 4;
  float* dst = Wf + (size_t)p * EDIM * EDIM + base;
  if (*flag){
    float4 v = *(const float4*)((const float*)W + base);
    *(float4*)dst = v;
  } else {
    ushort4 w = *(const ushort4*)((const unsigned short*)W + base);
    dst[0] = bf2f(w.x); dst[1] = bf2f(w.y); dst[2] = bf2f(w.z); dst[3] = bf2f(w.w);
  }
}

// K0: column sum-of-squares, parallel over 24 blocks (znacc pre-zeroed; sqrt in K1)
__global__ __launch_bounds__(256) void zn_accum_kernel(const float* __restrict__ Wf,
                                                       float* __restrict__ znacc){
  const int p = blockIdx.x >> 3;
  const int chunk = blockIdx.x & 7;
  const float* W = Wf + (size_t)p * EDIM * EDIM + (size_t)chunk * 64 * EDIM;
  const int o0 = threadIdx.x * 2;
  float a0 = 0.f, a1 = 0.f;
  #pragma unroll 4
  for (int i = 0; i < 64; ++i){
    float2 z = *(const float2*)&W[i * EDIM + o0];
    a0 += z.x * z.x; a1 += z.y * z.y;
  }
  atomicAdd(&znacc[p * EDIM + o0], a0);
  atomicAdd(&znacc[p * EDIM + o0 + 1], a1);
}

// K1: hyperbolic linear. 16 rows/block. Writes bf16 q/k/v [p][h][s][d] + squared norms
// of the ROUNDED values. Fast closed-form sinh(2zn*asinh(a)) via __logf/__expf.
__global__ __launch_bounds__(256) void hlinear_kernel(
    const void* __restrict__ Xq, const void* __restrict__ Xk, const void* __restrict__ Xv,
    const float* __restrict__ Wf,
    const void* __restrict__ Bq, const void* __restrict__ Bk, const void* __restrict__ Bv,
    const float* __restrict__ znacc, const int* __restrict__ flag,
    unsigned short* __restrict__ qkvb, float* __restrict__ stats)
{
  const int p = blockIdx.y;
  const void* X  = (p == 0) ? Xq : ((p == 1) ? Xk : Xv);
  const void* Bb = (p == 0) ? Bq : ((p == 1) ? Bk : Bv);
  const float* W = Wf + (size_t)p * EDIM * EDIM;
  const int r0 = blockIdx.x * ROWS;
  const int t  = threadIdx.x;
  const int isf32 = *flag;

  __shared__ float smem[EDIM * XSTR];   // phase 1: xT [i][rr] stride 20; phase 2: w [rr][o]
  __shared__ float x2p[4][ROWS];
  __shared__ float x2s[ROWS];
  __shared__ float sw2[ROWS];

  float part[ROWS];
  #pragma unroll
  for (int rr = 0; rr < ROWS; ++rr) part[rr] = 0.f;
  if (isf32){
    const float* Xf = (const float*)X;
    for (int i = t; i < EDIM; i += 256){
      #pragma unroll
      for (int rr = 0; rr < ROWS; ++rr){
        float xv = Xf[(size_t)(r0 + rr) * EDIM + i];
        smem[i * XSTR + rr] = xv;
        part[rr] += xv * xv;
      }
    }
  } else {
    const unsigned short* Xb = (const unsigned short*)X;
    for (int i = t; i < EDIM; i += 256){
      #pragma unroll
      for (int rr = 0; rr < ROWS; ++rr){
        float xv = bf2f(Xb[(size_t)(r0 + rr) * EDIM + i]);
        smem[i * XSTR + rr] = xv;
        part[rr] += xv * xv;
      }
    }
  }
  #pragma unroll
  for (int rr = 0; rr < ROWS; ++rr){
    float v = part[rr];
    #pragma unroll
    for (int m = 32; m >= 1; m >>= 1) v += __shfl_xor(v, m, 64);
    if ((t & 63) == 0) x2p[t >> 6][rr] = v;
  }
  __syncthreads();
  if (t < ROWS) x2s[t] = x2p[0][t] + x2p[1][t] + x2p[2][t] + x2p[3][t];
  __syncthreads();

  const int o0 = 2 * t;
  float acc[ROWS][2];
  #pragma unroll
  for (int rr = 0; rr < ROWS; ++rr){ acc[rr][0] = 0.f; acc[rr][1] = 0.f; }

  #pragma unroll 4
  for (int i = 0; i < EDIM; ++i){
    float2 z = *(const float2*)&W[i * EDIM + o0];
    float4 xa = *(const float4*)&smem[i * XSTR];
    float4 xb = *(const float4*)&smem[i * XSTR + 4];
    float4 xc = *(const float4*)&smem[i * XSTR + 8];
    float4 xd = *(const float4*)&smem[i * XSTR + 12];
    float xr[ROWS] = {xa.x, xa.y, xa.z, xa.w, xb.x, xb.y, xb.z, xb.w,
                      xc.x, xc.y, xc.z, xc.w, xd.x, xd.y, xd.z, xd.w};
    #pragma unroll
    for (int rr = 0; rr < ROWS; ++rr){
      acc[rr][0] += xr[rr] * z.x;
      acc[rr][1] += xr[rr] * z.y;
    }
  }
  __syncthreads();   // done reading xT; smem reused for w values

  {
    float rb0, rb1;
    if (isf32){ rb0 = ((const float*)Bb)[o0]; rb1 = ((const float*)Bb)[o0 + 1]; }
    else      { rb0 = bf2f(((const unsigned short*)Bb)[o0]);
                rb1 = bf2f(((const unsigned short*)Bb)[o0 + 1]); }
    float znv  = fmaxf(sqrtf(znacc[p * EDIM + o0]), EPSF);
    float znv1 = fmaxf(sqrtf(znacc[p * EDIM + o0 + 1]), EPSF);
    float ch0 = coshf(2.f * rb0), sh0 = sinhf(2.f * rb0);
    float ch1 = coshf(2.f * rb1), sh1 = sinhf(2.f * rb1);
    float tz0 = 2.f * znv, tz1 = 2.f * znv1;
    #pragma unroll
    for (int rr = 0; rr < ROWS; ++rr){
      float lam = 2.f / (1.f - x2s[rr]);
      float a0 = (acc[rr][0] * lam / znv)  * ch0 - (lam - 1.f) * sh0;
      float a1 = (acc[rr][1] * lam / znv1) * ch1 - (lam - 1.f) * sh1;
      // sinh(tz*asinh(a)) = 0.5*(b^tz - b^-tz), b = a+sqrt(a^2+1)
      float b0 = a0 + sqrtf(a0 * a0 + 1.f);
      float b1 = a1 + sqrtf(a1 * a1 + 1.f);
      float t0 = __expf(tz0 * __logf(b0));
      float t1 = __expf(tz1 * __logf(b1));
      smem[rr * EDIM + o0]     = 0.5f * (t0 - 1.f / t0);
      smem[rr * EDIM + o0 + 1] = 0.5f * (t1 - 1.f / t1);
    }
  }
  __syncthreads();

  {
    int row = t >> 4, l = t & 15;
    float s = 0.f;
    for (int o = l; o < EDIM; o += 16){ float wv = smem[row * EDIM + o]; s += wv * wv; }
    #pragma unroll
    for (int m = 8; m >= 1; m >>= 1) s += __shfl_xor(s, m, 16);
    if (l == 0) sw2[row] = s;
  }
  __syncthreads();

  const int h0 = t >> 5;
  const int d0 = o0 & 63;
  #pragma unroll
  for (int rr = 0; rr < ROWS; ++rr){
    float inv = 1.f / (1.f + sqrtf(1.f + sw2[rr]));
    unsigned short b0 = f2bf(smem[rr * EDIM + o0] * inv);
    unsigned short b1 = f2bf(smem[rr * EDIM + o0 + 1] * inv);
    float r0v = bf2f(b0), r1v = bf2f(b1);   // rounded values for stats
    int s = r0 + rr;
    unsigned int* dst = (unsigned int*)&qkvb[(((size_t)p * H + h0) * SEQ + s) * HD + d0];
    *dst = (unsigned int)b0 | ((unsigned int)b1 << 16);
    float ss = r0v * r0v + r1v * r1v;
    #pragma unroll
    for (int m = 16; m >= 1; m >>= 1) ss += __shfl_xor(ss, m, 64);
    if ((t & 31) == 0) stats[((size_t)p * H + h0) * SEQ + s] = ss;
  }
}

// K2: build VT' = [lambda_k * v | lambda_k - 1 | zero-pad] bf16, layout [h][80][SEQ]
__global__ __launch_bounds__(256) void vt_kernel(
    const unsigned short* __restrict__ Vb, const float* __restrict__ v2s,
    unsigned short* __restrict__ VT)
{
  const int h = blockIdx.y;
  const int k0 = blockIdx.x * 64;
  const int t = threadIdx.x;
  __shared__ float tld[64][65];
  __shared__ float lam[64];
  if (t < 64){ float v2 = v2s[(size_t)h * SEQ + k0 + t]; lam[t] = 2.f / (1.f - v2); }
  #pragma unroll
  for (int i = 0; i < 16; ++i){
    int idx = t * 16 + i;
    int kk = idx >> 6, d = idx & 63;
    tld[kk][d] = bf2f(Vb[((size_t)h * SEQ + k0 + kk) * HD + d]);
  }
  __syncthreads();
  const int d = t >> 2;
  const int kb = (t & 3) * 16;
  #pragma unroll
  for (int i = 0; i < 16; ++i){
    int k = kb + i;
    float val = tld[k][d] * lam[k];
    VT[((size_t)h * 80 + d) * SEQ + k0 + k] = f2bf(val);
  }
  if (t < 64) VT[((size_t)h * 80 + 64) * SEQ + k0 + t] = f2bf(lam[t] - 1.f);
  #pragma unroll
  for (int i = 0; i < 4; ++i){
    int e = t + 256 * i;
    if (e < 960){
      int row = 65 + (e >> 6), kk = e & 63;
      VT[((size_t)h * 80 + row) * SEQ + k0 + kk] = 0;
    }
  }
}

// K3: MFMA causal hyperbolic attention, S^T orientation, shuffle P-transpose.
// k-SPLIT: block = 4 waves on ONE q-tile; wave w takes chunks w, w+4, ...;
// partial pv reduced through LDS; wave 0 does the epilogue.
__global__ __launch_bounds__(256) void attn_mfma_kernel(
    const unsigned short* __restrict__ Qb, const unsigned short* __restrict__ Kb,
    const unsigned short* __restrict__ VT,
    const float* __restrict__ q2s_all, const float* __restrict__ k2s_all,
    const void* __restrict__ tau, const void* __restrict__ gam,
    const int* __restrict__ flag,
    float* __restrict__ out, float beta_scale)
{
  const int h  = blockIdx.y;
  const int tile = blockIdx.x;           // 0..127
  const int t = threadIdx.x;
  const int w = t >> 6, lane = t & 63;
  const int col = lane & 15, quad = lane >> 4;
  const int q0 = tile * 16;

  const unsigned short* Qh  = Qb + (size_t)h * SEQ * HD;
  const unsigned short* Kh  = Kb + (size_t)h * SEQ * HD;
  const unsigned short* VTh = VT + (size_t)h * 80 * SEQ;
  const float* q2s = q2s_all + (size_t)h * SEQ;
  const float* k2s = k2s_all + (size_t)h * SEQ;

  __shared__ float red[4][64][20];

  float tauv, gamv;
  if (*flag){ tauv = ((const float*)tau)[0]; gamv = ((const float*)gam)[0]; }
  else      { tauv = bf2f(((const unsigned short*)tau)[0]);
              gamv = bf2f(((const unsigned short*)gam)[0]); }
  const float e_tau = expf(tauv);

  // shuffle sources for C-layout -> A-layout transpose (uniform per lane)
  const int srcA = ((quad & 1) * 2) * 16 + col;
  const int srcB = srcA + 16;
  const int tsel = quad >> 1;

  // Q as B-frag: row (q0+col), dims quad*8.. (+32)
  bf16x8 qf0 = *(const bf16x8*)&Qh[(size_t)(q0 + col) * HD + quad * 8];
  bf16x8 qf1 = *(const bf16x8*)&Qh[(size_t)(q0 + col) * HD + 32 + quad * 8];
  const float q2 = q2s[q0 + col];
  const float omq2 = 1.f - q2;
  const int qmax = q0 + col;

  f32x4 pv[5];
  #pragma unroll
  for (int nt = 0; nt < 5; ++nt) pv[nt] = (f32x4){0.f, 0.f, 0.f, 0.f};

  const int nch = (tile + 4) >> 2;   // chunks of 64 keys
  for (int kc = w; kc < nch; kc += 4){
    #pragma unroll
    for (int half = 0; half < 2; ++half){
      const int kb32 = kc * 64 + half * 32;
      unsigned int tlo[2], thi[2];
      #pragma unroll
      for (int tt = 0; tt < 2; ++tt){
        const int kbase = kb32 + 16 * tt;
        bf16x8 kf0 = *(const bf16x8*)&Kh[(size_t)(kbase + col) * HD + quad * 8];
        bf16x8 kf1 = *(const bf16x8*)&Kh[(size_t)(kbase + col) * HD + 32 + quad * 8];
        f32x4 s = (f32x4){0.f, 0.f, 0.f, 0.f};
        s = __builtin_amdgcn_mfma_f32_16x16x32_bf16(kf0, qf0, s, 0, 0, 0);
        s = __builtin_amdgcn_mfma_f32_16x16x32_bf16(kf1, qf1, s, 0, 0, 0);
        // S^T: lane holds [key=kbase+quad*4+r][q=q0+col]
        float4 k2q = *(const float4*)&k2s[kbase + quad * 4];
        unsigned short pb[4];
        #pragma unroll
        for (int r = 0; r < 4; ++r){
          float k2 = (r == 0) ? k2q.x : (r == 1) ? k2q.y : (r == 2) ? k2q.z : k2q.w;
          float diff2 = fmaxf(q2 + k2 - 2.f * s[r], 0.f);
          float u = 2.f * diff2 / (omq2 * (1.f - k2));
          u = fmaxf(u, 1e-7f);                           // ref's arg>=1+1e-7 clamp
          float z = 1.f + u + sqrtf(u * (u + 2.f));      // arg + sqrt(arg^2-1), stable
          float dist = __logf(z);
          float wv = __expf(-e_tau * dist - gamv);
          int key = kbase + quad * 4 + r;
          if (key > qmax) wv = 0.f;
          pb[r] = f2bf(wv);
        }
        tlo[tt] = (unsigned int)pb[0] | ((unsigned int)pb[1] << 16);
        thi[tt] = (unsigned int)pb[2] | ((unsigned int)pb[3] << 16);
      }
      // cross-lane transpose: pf[j] = P[q=col][key=kb32+quad*8+j]
      unsigned int a0 = (unsigned int)__shfl((int)tlo[0], srcA, 64);
      unsigned int a1 = (unsigned int)__shfl((int)tlo[1], srcA, 64);
      unsigned int b0 = (unsigned int)__shfl((int)thi[0], srcA, 64);
      unsigned int b1 = (unsigned int)__shfl((int)thi[1], srcA, 64);
      unsigned int c0 = (unsigned int)__shfl((int)tlo[0], srcB, 64);
      unsigned int c1 = (unsigned int)__shfl((int)tlo[1], srcB, 64);
      unsigned int d0 = (unsigned int)__shfl((int)thi[0], srcB, 64);
      unsigned int d1 = (unsigned int)__shfl((int)thi[1], srcB, 64);
      union { uint4 u; bf16x8 v; } pw;
      pw.u.x = tsel ? a1 : a0;
      pw.u.y = tsel ? b1 : b0;
      pw.u.z = tsel ? c1 : c0;
      pw.u.w = tsel ? d1 : d0;
      // P x VT' (K=32)
      #pragma unroll
      for (int nt = 0; nt < 5; ++nt){
        bf16x8 vf = *(const bf16x8*)&VTh[(size_t)(16 * nt + col) * SEQ + kb32 + quad * 8];
        pv[nt] = __builtin_amdgcn_mfma_f32_16x16x32_bf16(pw.v, vf, pv[nt], 0, 0, 0);
      }
    }
  }

  // block reduction of partial pv
  #pragma unroll
  for (int nt = 0; nt < 5; ++nt)
    *(float4*)&red[w][lane][nt * 4] = (float4){pv[nt][0], pv[nt][1], pv[nt][2], pv[nt][3]};
  __syncthreads();

  if (t < 64){
    #pragma unroll
    for (int nt = 0; nt < 5; ++nt){
      float4 a = *(const float4*)&red[0][t][nt * 4];
      float4 b = *(const float4*)&red[1][t][nt * 4];
      float4 c = *(const float4*)&red[2][t][nt * 4];
      float4 d = *(const float4*)&red[3][t][nt * 4];
      pv[nt][0] = a.x + b.x + c.x + d.x;
      pv[nt][1] = a.y + b.y + c.y + d.y;
      pv[nt][2] = a.z + b.z + c.z + d.z;
      pv[nt][3] = a.w + b.w + c.w + d.w;
    }
    // gyromidpoint epilogue (wave 0 only): lane holds O[q=q0+quad*4+r][odim=16nt+col]
    #pragma unroll
    for (int r = 0; r < 4; ++r){
      float den = __shfl(pv[4][r], quad * 16, 64);   // col 64 lives at col==0 lanes
      den = fmaxf(den, EPSF);
      float inv_den = 1.f / den;
      float g[4];
      float gsq = 0.f;
      #pragma unroll
      for (int nt = 0; nt < 4; ++nt){ g[nt] = pv[nt][r] * inv_den; gsq += g[nt] * g[nt]; }
      #pragma unroll
      for (int m = 8; m >= 1; m >>= 1) gsq += __shfl_xor(gsq, m, 64);
      float gn = fmaxf(sqrtf(gsq), EPSF);
      float x = fminf(gn, 1.f - 1e-7f);
      float tt2 = x / (1.f + sqrtf(1.f - x * x));   // tanh(0.5*atanh(x))
      float scl = (tt2 / gn) * beta_scale;
      const int q = q0 + quad * 4 + r;
      #pragma unroll
      for (int nt = 0; nt < 4; ++nt)
        out[(size_t)q * EDIM + h * HD + 16 * nt + col] = g[nt] * scl;
    }
  }
}

extern "C" void kernel_launch(void* const* d_in, const int* in_sizes, int n_in,
                              void* d_out, int out_size, void* d_ws, size_t ws_size,
                              hipStream_t stream){
  const void* Xq  = d_in[0];
  const void* Xk  = d_in[1];
  const void* Xv  = d_in[2];
  const void* Wq  = d_in[3];
  const void* Wk  = d_in[4];
  const void* Wv  = d_in[5];
  const void* Bq  = d_in[6];
  const void* Bk  = d_in[7];
  const void* Bv  = d_in[8];
  const void* tau = d_in[9];
  const void* gam = d_in[10];

  float* wsf   = (float*)d_ws;
  int*   flag  = (int*)(wsf + FLAG_OFF);
  float* Wf    = wsf + WF_OFF;
  float* zn    = wsf + ZN_OFF;
  float* stats = wsf + STATS_OFF;
  unsigned short* qkvb = (unsigned short*)(wsf + QKVB_OFF);
  unsigned short* VT   = (unsigned short*)(wsf + VT_OFF);

  unsigned short* Qb = qkvb;
  unsigned short* Kb = qkvb + (size_t)H * SEQ * HD;
  unsigned short* Vb = qkvb + (size_t)2 * H * SEQ * HD;
  float* q2s = stats;
  float* k2s = stats + (size_t)H * SEQ;
  float* v2s = stats + (size_t)2 * H * SEQ;

  double lb1 = lgamma(EDIM / 2.0) + lgamma(0.5) - lgamma(EDIM / 2.0 + 0.5);
  double lb2 = lgamma(HD / 2.0)   + lgamma(0.5) - lgamma(HD / 2.0 + 0.5);
  float beta_scale = (float)exp(lb1 - lb2);

  probe_kernel<<<dim3(1), dim3(64), 0, stream>>>((const unsigned short*)Xq, flag);
  wcvt_kernel<<<dim3(256, 3), dim3(256), 0, stream>>>(Wq, Wk, Wv, flag, Wf);
  hipMemsetAsync(zn, 0, 3 * EDIM * sizeof(float), stream);
  zn_accum_kernel<<<dim3(24), dim3(256), 0, stream>>>(Wf, zn);
  hlinear_kernel<<<dim3(SEQ / ROWS, 3), dim3(256), 0, stream>>>(
      Xq, Xk, Xv, Wf, Bq, Bk, Bv, zn, flag, qkvb, stats);
  vt_kernel<<<dim3(SEQ / 64, H), dim3(256), 0, stream>>>(Vb, v2s, VT);
  attn_mfma_kernel<<<dim3(SEQ / 16, H), dim3(256), 0, stream>>>(
      Qb, Kb, VT, q2s, k2s, tau, gam, flag, (float*)d_out, beta_scale);
}

// Round 9
// 231.327 us; speedup vs baseline: 2.3759x; 1.0351x over previous
//
#include <hip/hip_runtime.h>
#include <cmath>

#define H 8
#define SEQ 2048
#define EDIM 512
#define HD 64
#define EPSF 1e-15f

typedef short bf16x8 __attribute__((ext_vector_type(8)));
typedef float f32x4 __attribute__((ext_vector_type(4)));

// workspace layout (float offsets; 16B-aligned)
#define FLAG_OFF  0
#define ZN_OFF    16
#define X2S_OFF   (ZN_OFF + 3 * EDIM)          // 3*SEQ fp32
#define STATS_OFF (X2S_OFF + 3 * SEQ)          // 3*H*SEQ fp32
#define U16_OFF   (STATS_OFF + 3 * H * SEQ + 16)
// u16 sub-offsets (in u16 units) from the u16 base:
#define WT_U16    0
#define XB_U16    (WT_U16 + 3 * EDIM * EDIM)
#define QKVB_U16  (XB_U16 + 3 * SEQ * EDIM)
#define VT_U16    (QKVB_U16 + 3 * SEQ * EDIM)
// VT size: H*80*SEQ u16

__device__ __forceinline__ float bf2f(unsigned short u){
  union { unsigned int i; float f; } v; v.i = ((unsigned int)u) << 16; return v.f;
}
__device__ __forceinline__ unsigned short f2bf(float f){
  union { float f; unsigned int i; } v; v.f = f;
  unsigned int x = v.i;
  unsigned int r = (x + 0x7fffu + ((x >> 16) & 1u)) >> 16;
  return (unsigned short)r;
}

// P0: dtype probe (fp32 data bf16-decodes to huge magnitudes w.p. ~1)
__global__ void probe_kernel(const unsigned short* __restrict__ q, int* __restrict__ flag){
  const int t = threadIdx.x;  // 64
  float mx = 0.f;
  #pragma unroll
  for (int j = 0; j < 4; ++j) mx = fmaxf(mx, fabsf(bf2f(q[t * 4 + j])));
  #pragma unroll
  for (int m = 32; m >= 1; m >>= 1) mx = fmaxf(mx, __shfl_xor(mx, m, 64));
  if (t == 0) *flag = (mx > 1000.f) ? 1 : 0;
}

// P1: W -> WT bf16 [p][o][i] (transpose) + fp32 column sumsq into zn (pre-zeroed).
__global__ __launch_bounds__(256) void wcvt_kernel(
    const void* __restrict__ Wq, const void* __restrict__ Wk, const void* __restrict__ Wv,
    const int* __restrict__ flag, unsigned short* __restrict__ WT, float* __restrict__ zn)
{
  const int p = blockIdx.y;
  const int bi = blockIdx.x >> 3, bo = blockIdx.x & 7;
  const void* W = (p == 0) ? Wq : ((p == 1) ? Wk : Wv);
  const int t = threadIdx.x;
  const int isf32 = *flag;
  __shared__ float tile[64][65];

  #pragma unroll
  for (int j = 0; j < 16; ++j){
    int idx = t + 256 * j;
    int il = idx >> 6, ol = idx & 63;
    float val;
    if (isf32) val = ((const float*)W)[(size_t)(bi * 64 + il) * EDIM + bo * 64 + ol];
    else       val = bf2f(((const unsigned short*)W)[(size_t)(bi * 64 + il) * EDIM + bo * 64 + ol]);
    tile[il][ol] = val;
  }
  __syncthreads();
  if (t < 64){
    float s = 0.f;
    #pragma unroll 8
    for (int i = 0; i < 64; ++i){ float v = tile[i][t]; s += v * v; }
    atomicAdd(&zn[p * EDIM + bo * 64 + t], s);
  }
  #pragma unroll
  for (int j = 0; j < 16; ++j){
    int idx = t + 256 * j;
    int ol = idx >> 6, il = idx & 63;
    WT[((size_t)p * EDIM + bo * 64 + ol) * EDIM + bi * 64 + il] = f2bf(tile[il][ol]);
  }
}

// P2: X -> Xb bf16 [p][s][i] + exact fp32 row norms x2s[p][s].
__global__ __launch_bounds__(256) void xcvt_kernel(
    const void* __restrict__ Xq, const void* __restrict__ Xk, const void* __restrict__ Xv,
    const int* __restrict__ flag, unsigned short* __restrict__ Xb, float* __restrict__ x2s)
{
  const int p = blockIdx.y;
  const void* X = (p == 0) ? Xq : ((p == 1) ? Xk : Xv);
  const int row = blockIdx.x * 8 + (threadIdx.x >> 5);
  const int l = threadIdx.x & 31;
  const int isf32 = *flag;
  float s = 0.f;
  #pragma unroll
  for (int j = 0; j < 16; ++j){
    int i = l + 32 * j;
    float val;
    if (isf32) val = ((const float*)X)[(size_t)row * EDIM + i];
    else       val = bf2f(((const unsigned short*)X)[(size_t)row * EDIM + i]);
    Xb[((size_t)p * SEQ + row) * EDIM + i] = f2bf(val);
    s += val * val;
  }
  #pragma unroll
  for (int m = 16; m >= 1; m >>= 1) s += __shfl_xor(s, m, 64);
  if (l == 0) x2s[p * SEQ + row] = s;
}

// K1: hyperbolic linear via MFMA. Block = 4 waves = 8 seq rows x 512 cols.
// A-frags from L2 (Xb bf16), B-frags from WT bf16 (same pattern as attn's VT).
// fp32 transform -> smem -> verified normalization tail; fuses VT build for p==2.
__global__ __launch_bounds__(256) void hlinear_kernel(
    const unsigned short* __restrict__ Xb, const unsigned short* __restrict__ WT,
    const void* __restrict__ Bq, const void* __restrict__ Bk, const void* __restrict__ Bv,
    const float* __restrict__ znacc, const float* __restrict__ x2s_g,
    const int* __restrict__ flag,
    unsigned short* __restrict__ qkvb, float* __restrict__ stats,
    unsigned short* __restrict__ VT)
{
  const int p = blockIdx.y;
  const void* Bb = (p == 0) ? Bq : ((p == 1) ? Bk : Bv);
  const int r0 = blockIdx.x * 8;
  const int t  = threadIdx.x;
  const int w = t >> 6, lane = t & 63;
  const int col = lane & 15, quad = lane >> 4;
  const int isf32 = *flag;

  __shared__ float smem[8 * EDIM];   // w values [rr][o] fp32
  __shared__ float sw2[8];

  // ---- MFMA GEMM: rows r0..r0+7 (lanes col>=8 duplicate rows, ignored) ----
  const unsigned short* Xrow = Xb + ((size_t)p * SEQ + r0 + (col & 7)) * EDIM;
  const unsigned short* WTb  = WT + ((size_t)p * EDIM + w * 128 + col) * EDIM;

  f32x4 acc[8];
  #pragma unroll
  for (int nt = 0; nt < 8; ++nt) acc[nt] = (f32x4){0.f, 0.f, 0.f, 0.f};

  for (int ks = 0; ks < 16; ++ks){
    bf16x8 af = *(const bf16x8*)&Xrow[ks * 32 + quad * 8];
    #pragma unroll
    for (int nt = 0; nt < 8; ++nt){
      bf16x8 bf = *(const bf16x8*)&WTb[(size_t)nt * 16 * EDIM + ks * 32 + quad * 8];
      acc[nt] = __builtin_amdgcn_mfma_f32_16x16x32_bf16(af, bf, acc[nt], 0, 0, 0);
    }
  }

  // ---- transform (only quad<2 lanes hold valid rows m = quad*4+r < 8) ----
  if (quad < 2){
    float lamr[4], lm1[4];
    #pragma unroll
    for (int r = 0; r < 4; ++r){
      float x2 = x2s_g[p * SEQ + r0 + quad * 4 + r];
      lamr[r] = 2.f / (1.f - x2);
      lm1[r] = lamr[r] - 1.f;
    }
    #pragma unroll
    for (int nt = 0; nt < 8; ++nt){
      const int n = w * 128 + nt * 16 + col;
      float znv = fmaxf(sqrtf(znacc[p * EDIM + n]), EPSF);
      float rb;
      if (isf32) rb = ((const float*)Bb)[n];
      else       rb = bf2f(((const unsigned short*)Bb)[n]);
      float e2r = __expf(2.f * rb);
      float ie2r = 1.f / e2r;
      float ch = 0.5f * (e2r + ie2r), sh = 0.5f * (e2r - ie2r);
      float izn = 1.f / znv;
      float tz = 2.f * znv;
      #pragma unroll
      for (int r = 0; r < 4; ++r){
        float a = (acc[nt][r] * lamr[r] * izn) * ch - lm1[r] * sh;
        float b = a + sqrtf(a * a + 1.f);
        float tt = __expf(tz * __logf(b));
        smem[(quad * 4 + r) * EDIM + n] = 0.5f * (tt - 1.f / tt);
      }
    }
  }
  __syncthreads();

  // ---- per-row sum of w^2 (32 threads per row) ----
  {
    int row = t >> 5, l = t & 31;
    float s = 0.f;
    for (int o = l; o < EDIM; o += 32){ float wv = smem[row * EDIM + o]; s += wv * wv; }
    #pragma unroll
    for (int m = 16; m >= 1; m >>= 1) s += __shfl_xor(s, m, 64);
    if (l == 0) sw2[row] = s;
  }
  __syncthreads();

  // ---- normalize, write qkvb bf16 + per-head squared norms (+ fused VT for p==2) ----
  const int o0 = 2 * t;
  const int h0 = t >> 5;
  const int d0 = o0 & 63;
  #pragma unroll
  for (int rr = 0; rr < 8; ++rr){
    float inv = 1.f / (1.f + sqrtf(1.f + sw2[rr]));
    unsigned short b0 = f2bf(smem[rr * EDIM + o0] * inv);
    unsigned short b1 = f2bf(smem[rr * EDIM + o0 + 1] * inv);
    float r0v = bf2f(b0), r1v = bf2f(b1);   // rounded values for stats
    int s = r0 + rr;
    unsigned int* dst = (unsigned int*)&qkvb[(((size_t)p * H + h0) * SEQ + s) * HD + d0];
    *dst = (unsigned int)b0 | ((unsigned int)b1 << 16);
    float ss = r0v * r0v + r1v * r1v;
    #pragma unroll
    for (int m = 16; m >= 1; m >>= 1) ss += __shfl_xor(ss, m, 64);
    if (p == 2){
      float lam = 2.f / (1.f - ss);
      VT[((size_t)h0 * 80 + d0) * SEQ + s]     = f2bf(r0v * lam);
      VT[((size_t)h0 * 80 + d0 + 1) * SEQ + s] = f2bf(r1v * lam);
      if ((t & 31) == 0) VT[((size_t)h0 * 80 + 64) * SEQ + s] = f2bf(lam - 1.f);
    }
    if ((t & 31) == 0) stats[((size_t)p * H + h0) * SEQ + s] = ss;
  }
}

// K3: MFMA causal hyperbolic attention, S^T orientation, shuffle P-transpose.
// k-SPLIT: block = 4 waves on ONE q-tile; wave w takes chunks w, w+4, ...
__global__ __launch_bounds__(256) void attn_mfma_kernel(
    const unsigned short* __restrict__ Qb, const unsigned short* __restrict__ Kb,
    const unsigned short* __restrict__ VT,
    const float* __restrict__ q2s_all, const float* __restrict__ k2s_all,
    const void* __restrict__ tau, const void* __restrict__ gam,
    const int* __restrict__ flag,
    float* __restrict__ out, float beta_scale)
{
  const int h  = blockIdx.y;
  const int tile = blockIdx.x;           // 0..127
  const int t = threadIdx.x;
  const int w = t >> 6, lane = t & 63;
  const int col = lane & 15, quad = lane >> 4;
  const int q0 = tile * 16;

  const unsigned short* Qh  = Qb + (size_t)h * SEQ * HD;
  const unsigned short* Kh  = Kb + (size_t)h * SEQ * HD;
  const unsigned short* VTh = VT + (size_t)h * 80 * SEQ;
  const float* q2s = q2s_all + (size_t)h * SEQ;
  const float* k2s = k2s_all + (size_t)h * SEQ;

  __shared__ float red[4][64][20];

  float tauv, gamv;
  if (*flag){ tauv = ((const float*)tau)[0]; gamv = ((const float*)gam)[0]; }
  else      { tauv = bf2f(((const unsigned short*)tau)[0]);
              gamv = bf2f(((const unsigned short*)gam)[0]); }
  const float e_tau = expf(tauv);

  const int srcA = ((quad & 1) * 2) * 16 + col;
  const int srcB = srcA + 16;
  const int tsel = quad >> 1;

  bf16x8 qf0 = *(const bf16x8*)&Qh[(size_t)(q0 + col) * HD + quad * 8];
  bf16x8 qf1 = *(const bf16x8*)&Qh[(size_t)(q0 + col) * HD + 32 + quad * 8];
  const float q2 = q2s[q0 + col];
  const float omq2 = 1.f - q2;
  const int qmax = q0 + col;

  f32x4 pv[5];
  #pragma unroll
  for (int nt = 0; nt < 5; ++nt) pv[nt] = (f32x4){0.f, 0.f, 0.f, 0.f};

  const int nch = (tile + 4) >> 2;
  for (int kc = w; kc < nch; kc += 4){
    #pragma unroll
    for (int half = 0; half < 2; ++half){
      const int kb32 = kc * 64 + half * 32;
      unsigned int tlo[2], thi[2];
      #pragma unroll
      for (int tt = 0; tt < 2; ++tt){
        const int kbase = kb32 + 16 * tt;
        bf16x8 kf0 = *(const bf16x8*)&Kh[(size_t)(kbase + col) * HD + quad * 8];
        bf16x8 kf1 = *(const bf16x8*)&Kh[(size_t)(kbase + col) * HD + 32 + quad * 8];
        f32x4 s = (f32x4){0.f, 0.f, 0.f, 0.f};
        s = __builtin_amdgcn_mfma_f32_16x16x32_bf16(kf0, qf0, s, 0, 0, 0);
        s = __builtin_amdgcn_mfma_f32_16x16x32_bf16(kf1, qf1, s, 0, 0, 0);
        float4 k2q = *(const float4*)&k2s[kbase + quad * 4];
        unsigned short pb[4];
        #pragma unroll
        for (int r = 0; r < 4; ++r){
          float k2 = (r == 0) ? k2q.x : (r == 1) ? k2q.y : (r == 2) ? k2q.z : k2q.w;
          float diff2 = fmaxf(q2 + k2 - 2.f * s[r], 0.f);
          float u = 2.f * diff2 / (omq2 * (1.f - k2));
          u = fmaxf(u, 1e-7f);
          float z = 1.f + u + sqrtf(u * (u + 2.f));
          float dist = __logf(z);
          float wv = __expf(-e_tau * dist - gamv);
          int key = kbase + quad * 4 + r;
          if (key > qmax) wv = 0.f;
          pb[r] = f2bf(wv);
        }
        tlo[tt] = (unsigned int)pb[0] | ((unsigned int)pb[1] << 16);
        thi[tt] = (unsigned int)pb[2] | ((unsigned int)pb[3] << 16);
      }
      unsigned int a0 = (unsigned int)__shfl((int)tlo[0], srcA, 64);
      unsigned int a1 = (unsigned int)__shfl((int)tlo[1], srcA, 64);
      unsigned int b0 = (unsigned int)__shfl((int)thi[0], srcA, 64);
      unsigned int b1 = (unsigned int)__shfl((int)thi[1], srcA, 64);
      unsigned int c0 = (unsigned int)__shfl((int)tlo[0], srcB, 64);
      unsigned int c1 = (unsigned int)__shfl((int)tlo[1], srcB, 64);
      unsigned int d0 = (unsigned int)__shfl((int)thi[0], srcB, 64);
      unsigned int d1 = (unsigned int)__shfl((int)thi[1], srcB, 64);
      union { uint4 u; bf16x8 v; } pw;
      pw.u.x = tsel ? a1 : a0;
      pw.u.y = tsel ? b1 : b0;
      pw.u.z = tsel ? c1 : c0;
      pw.u.w = tsel ? d1 : d0;
      #pragma unroll
      for (int nt = 0; nt < 5; ++nt){
        bf16x8 vf = *(const bf16x8*)&VTh[(size_t)(16 * nt + col) * SEQ + kb32 + quad * 8];
        pv[nt] = __builtin_amdgcn_mfma_f32_16x16x32_bf16(pw.v, vf, pv[nt], 0, 0, 0);
      }
    }
  }

  #pragma unroll
  for (int nt = 0; nt < 5; ++nt)
    *(float4*)&red[w][lane][nt * 4] = (float4){pv[nt][0], pv[nt][1], pv[nt][2], pv[nt][3]};
  __syncthreads();

  if (t < 64){
    #pragma unroll
    for (int nt = 0; nt < 5; ++nt){
      float4 a = *(const float4*)&red[0][t][nt * 4];
      float4 b = *(const float4*)&red[1][t][nt * 4];
      float4 c = *(const float4*)&red[2][t][nt * 4];
      float4 d = *(const float4*)&red[3][t][nt * 4];
      pv[nt][0] = a.x + b.x + c.x + d.x;
      pv[nt][1] = a.y + b.y + c.y + d.y;
      pv[nt][2] = a.z + b.z + c.z + d.z;
      pv[nt][3] = a.w + b.w + c.w + d.w;
    }
    #pragma unroll
    for (int r = 0; r < 4; ++r){
      float den = __shfl(pv[4][r], quad * 16, 64);
      den = fmaxf(den, EPSF);
      float inv_den = 1.f / den;
      float g[4];
      float gsq = 0.f;
      #pragma unroll
      for (int nt = 0; nt < 4; ++nt){ g[nt] = pv[nt][r] * inv_den; gsq += g[nt] * g[nt]; }
      #pragma unroll
      for (int m = 8; m >= 1; m >>= 1) gsq += __shfl_xor(gsq, m, 64);
      float gn = fmaxf(sqrtf(gsq), EPSF);
      float x = fminf(gn, 1.f - 1e-7f);
      float tt2 = x / (1.f + sqrtf(1.f - x * x));
      float scl = (tt2 / gn) * beta_scale;
      const int q = q0 + quad * 4 + r;
      #pragma unroll
      for (int nt = 0; nt < 4; ++nt)
        out[(size_t)q * EDIM + h * HD + 16 * nt + col] = g[nt] * scl;
    }
  }
}

extern "C" void kernel_launch(void* const* d_in, const int* in_sizes, int n_in,
                              void* d_out, int out_size, void* d_ws, size_t ws_size,
                              hipStream_t stream){
  const void* Xq  = d_in[0];
  const void* Xk  = d_in[1];
  const void* Xv  = d_in[2];
  const void* Wq  = d_in[3];
  const void* Wk  = d_in[4];
  const void* Wv  = d_in[5];
  const void* Bq  = d_in[6];
  const void* Bk  = d_in[7];
  const void* Bv  = d_in[8];
  const void* tau = d_in[9];
  const void* gam = d_in[10];

  float* wsf   = (float*)d_ws;
  int*   flag  = (int*)(wsf + FLAG_OFF);
  float* zn    = wsf + ZN_OFF;
  float* x2s   = wsf + X2S_OFF;
  float* stats = wsf + STATS_OFF;
  unsigned short* u16b = (unsigned short*)(wsf + U16_OFF);
  unsigned short* WT   = u16b + WT_U16;
  unsigned short* Xb   = u16b + XB_U16;
  unsigned short* qkvb = u16b + QKVB_U16;
  unsigned short* VT   = u16b + VT_U16;

  unsigned short* Qb = qkvb;
  unsigned short* Kb = qkvb + (size_t)H * SEQ * HD;
  float* q2s = stats;
  float* k2s = stats + (size_t)H * SEQ;

  double lb1 = lgamma(EDIM / 2.0) + lgamma(0.5) - lgamma(EDIM / 2.0 + 0.5);
  double lb2 = lgamma(HD / 2.0)   + lgamma(0.5) - lgamma(HD / 2.0 + 0.5);
  float beta_scale = (float)exp(lb1 - lb2);

  probe_kernel<<<dim3(1), dim3(64), 0, stream>>>((const unsigned short*)Xq, flag);
  hipMemsetAsync(zn, 0, 3 * EDIM * sizeof(float), stream);
  hipMemsetAsync(VT, 0, (size_t)H * 80 * SEQ * sizeof(unsigned short), stream);
  wcvt_kernel<<<dim3(64, 3), dim3(256), 0, stream>>>(Wq, Wk, Wv, flag, WT, zn);
  xcvt_kernel<<<dim3(SEQ / 8, 3), dim3(256), 0, stream>>>(Xq, Xk, Xv, flag, Xb, x2s);
  hlinear_kernel<<<dim3(SEQ / 8, 3), dim3(256), 0, stream>>>(
      Xb, WT, Bq, Bk, Bv, zn, x2s, flag, qkvb, stats, VT);
  attn_mfma_kernel<<<dim3(SEQ / 16, H), dim3(256), 0, stream>>>(
      Qb, Kb, VT, q2s, k2s, tau, gam, flag, (float*)d_out, beta_scale);
}